// Round 8
// baseline (305.754 us; speedup 1.0000x reference)
//
#include <hip/hip_runtime.h>
#include <hip/hip_bf16.h>

namespace {

constexpr int B = 32, S = 512, E = 512, H = 8, P = 64, FF = 1536;
constexpr int BS = B * S;

typedef short v8s __attribute__((ext_vector_type(8)));
typedef float v4f __attribute__((ext_vector_type(4)));

__device__ __forceinline__ float bf2f(unsigned short u) {
  return __uint_as_float(((unsigned int)u) << 16);
}
__device__ __forceinline__ unsigned short f2bf(float f) {
  __hip_bfloat16 h = __float2bfloat16(f);
  return *reinterpret_cast<unsigned short*>(&h);
}

// ---------------- prep: weight transposes (blocks 0..447) + x->bf16/colsum (448..703) ----
__global__ __launch_bounds__(256) void k_prep(const float* __restrict__ w1, const float* __restrict__ w2,
                                              const float* __restrict__ wv, const float* __restrict__ x,
                                              unsigned short* __restrict__ w1t, unsigned short* __restrict__ w2t,
                                              unsigned short* __restrict__ wvt, unsigned short* __restrict__ xb,
                                              float* __restrict__ xsump) {
  __shared__ float tile[64][65];
  int id = blockIdx.x;
  int t = threadIdx.x;
  if (id >= 448) {
    int i = id - 448;
    int b = i >> 3, ch = i & 7;
    int c4 = (t & 127) * 4;
    int rh = t >> 7;
    const float* xp = x + ((size_t)b * S + ch * 64 + rh * 32) * E;
    unsigned short* xbp = xb + ((size_t)b * S + ch * 64 + rh * 32) * E;
    float ax = 0.f, ay = 0.f, az = 0.f, aw = 0.f;
    for (int s = 0; s < 32; ++s) {
      float4 v = *(const float4*)(xp + (size_t)s * E + c4);
      ax += v.x; ay += v.y; az += v.z; aw += v.w;
      ushort4 u;
      u.x = f2bf(v.x); u.y = f2bf(v.y); u.z = f2bf(v.z); u.w = f2bf(v.w);
      *(ushort4*)(xbp + (size_t)s * E + c4) = u;
    }
    float* xs = xsump + ((size_t)b * 16 + ch * 2 + rh) * E + c4;
    xs[0] = ax; xs[1] = ay; xs[2] = az; xs[3] = aw;
    return;
  }
  const float* inp;
  unsigned short* outp;
  int R, C, bx, by;
  size_t zo = 0;
  if (id < 192) {
    inp = w1; outp = w1t; R = 512; C = 1536; bx = id % 24; by = id / 24;
  } else if (id < 384) {
    int i = id - 192;
    inp = w2; outp = w2t; R = 1536; C = 512; bx = i & 7; by = i >> 3;
  } else {
    int i = id - 384;
    inp = wv; outp = wvt; R = 512; C = 64; bx = 0; by = i & 7; zo = (size_t)(i >> 3) * (512 * 64);
  }
  int c0 = bx * 64, r0 = by * 64;
#pragma unroll
  for (int j = 0; j < 4; ++j) {
    int i = t + j * 256;
    int rr = i >> 4, c4 = i & 15;
    float4 v = *(const float4*)(inp + zo + (size_t)(r0 + rr) * C + c0 + c4 * 4);
    tile[rr][c4 * 4 + 0] = v.x;
    tile[rr][c4 * 4 + 1] = v.y;
    tile[rr][c4 * 4 + 2] = v.z;
    tile[rr][c4 * 4 + 3] = v.w;
  }
  __syncthreads();
#pragma unroll
  for (int j = 0; j < 4; ++j) {
    int u = t + j * 256;
    int cr = u >> 4, q = u & 15;
    ushort4 o;
    o.x = f2bf(tile[q * 4 + 0][cr]);
    o.y = f2bf(tile[q * 4 + 1][cr]);
    o.z = f2bf(tile[q * 4 + 2][cr]);
    o.w = f2bf(tile[q * 4 + 3][cr]);
    *(ushort4*)(outp + zo + (size_t)(c0 + cr) * R + r0 + q * 4) = o;
  }
}

// ksum[p]=sum_e xsum[b,e]*wk[h,e,p]; wqk[b,h,e]=0.125*sum_p wq[h,e,p]*ksum[p]; zero sqnorm
__global__ __launch_bounds__(256) void k_wqk(const float* __restrict__ xsump, const float* __restrict__ wq,
                                             const float* __restrict__ wk, float* __restrict__ wqk,
                                             float* __restrict__ sqnorm) {
  int b = blockIdx.x, h = blockIdx.y, t = threadIdx.x;
  if (b == 0 && h == 0 && t < 8) sqnorm[t] = 0.f;
  __shared__ float xsl[E];
  __shared__ float ksp[4][64];
  __shared__ float ks[64];
#pragma unroll
  for (int j = 0; j < 2; ++j) {
    int e = t + j * 256;
    float s = 0.f;
#pragma unroll
    for (int c = 0; c < 16; ++c) s += xsump[((size_t)b * 16 + c) * E + e];
    xsl[e] = s;
  }
  __syncthreads();
  {
    const float* wkh = wk + (size_t)h * E * P;
    int p = t & 63, ec = t >> 6;
    float a = 0.f;
    for (int e = ec * 128; e < ec * 128 + 128; ++e) a += xsl[e] * wkh[e * 64 + p];
    ksp[ec][p] = a;
  }
  __syncthreads();
  if (t < 64) ks[t] = ksp[0][t] + ksp[1][t] + ksp[2][t] + ksp[3][t];
  __syncthreads();
  const float* wqh = wq + (size_t)h * E * P;
#pragma unroll
  for (int j = 0; j < 2; ++j) {
    int e = t + j * 256;
    float a = 0.f;
#pragma unroll 8
    for (int pp = 0; pp < P; ++pp) a += wqh[e * 64 + pp] * ks[pp];
    wqk[((size_t)b * H + h) * E + e] = a * 0.125f;
  }
}

// scores[b,h,s] = xb[b,s,:] . wqk[b,h,:]
__global__ __launch_bounds__(256) void k_scores(const unsigned short* __restrict__ xb,
                                                const float* __restrict__ wqk, float* __restrict__ scores) {
  int b = blockIdx.x, s0 = blockIdx.y * 64, t = threadIdx.x;
  __shared__ float xs[64][68];
  __shared__ float wt[8][68];
  float acc[2] = {0.f, 0.f};
  for (int ec = 0; ec < E; ec += 64) {
    {
      int row = t >> 2, cg = (t & 3) * 16;
      v8s v0 = *(const v8s*)(xb + ((size_t)b * S + s0 + row) * E + ec + cg);
      v8s v1 = *(const v8s*)(xb + ((size_t)b * S + s0 + row) * E + ec + cg + 8);
      float4 f0, f1, f2, f3;
      f0.x = bf2f((unsigned short)v0[0]); f0.y = bf2f((unsigned short)v0[1]);
      f0.z = bf2f((unsigned short)v0[2]); f0.w = bf2f((unsigned short)v0[3]);
      f1.x = bf2f((unsigned short)v0[4]); f1.y = bf2f((unsigned short)v0[5]);
      f1.z = bf2f((unsigned short)v0[6]); f1.w = bf2f((unsigned short)v0[7]);
      f2.x = bf2f((unsigned short)v1[0]); f2.y = bf2f((unsigned short)v1[1]);
      f2.z = bf2f((unsigned short)v1[2]); f2.w = bf2f((unsigned short)v1[3]);
      f3.x = bf2f((unsigned short)v1[4]); f3.y = bf2f((unsigned short)v1[5]);
      f3.z = bf2f((unsigned short)v1[6]); f3.w = bf2f((unsigned short)v1[7]);
      *(float4*)&xs[row][cg] = f0;
      *(float4*)&xs[row][cg + 4] = f1;
      *(float4*)&xs[row][cg + 8] = f2;
      *(float4*)&xs[row][cg + 12] = f3;
    }
    if (t < 128) {
      int hr = t >> 4, c4 = t & 15;
      float4 v = *(const float4*)(wqk + ((size_t)b * H + hr) * E + ec + c4 * 4);
      *(float4*)&wt[hr][c4 * 4] = v;
    }
    __syncthreads();
#pragma unroll
    for (int j = 0; j < 2; ++j) {
      int o = t + j * 256;
      int sl = o >> 3, hh = o & 7;
      float a = 0.f;
#pragma unroll
      for (int c4 = 0; c4 < 16; ++c4) {
        float4 xa = *(const float4*)&xs[sl][c4 * 4];
        float4 wa = *(const float4*)&wt[hh][c4 * 4];
        a += xa.x * wa.x + xa.y * wa.y + xa.z * wa.z + xa.w * wa.w;
      }
      acc[j] += a;
    }
    __syncthreads();
  }
#pragma unroll
  for (int j = 0; j < 2; ++j) {
    int o = t + j * 256;
    int sl = o >> 3, hh = o & 7;
    scores[((size_t)b * H + hh) * S + s0 + sl] = acc[j];
  }
}

__global__ __launch_bounds__(256) void k_softmax(const float* __restrict__ scores, float* __restrict__ attw,
                                                 float* __restrict__ att_out) {
  int bh = blockIdx.x, t = threadIdx.x;
  int b = bh >> 3, h = bh & 7;
  float v0 = scores[(size_t)bh * S + t];
  float v1 = scores[(size_t)bh * S + t + 256];
  float m = fmaxf(v0, v1);
#pragma unroll
  for (int off = 32; off; off >>= 1) m = fmaxf(m, __shfl_xor(m, off));
  __shared__ float rm[4], rs[4];
  if ((t & 63) == 0) rm[t >> 6] = m;
  __syncthreads();
  m = fmaxf(fmaxf(rm[0], rm[1]), fmaxf(rm[2], rm[3]));
  float e0 = __expf(v0 - m), e1 = __expf(v1 - m);
  float sm = e0 + e1;
#pragma unroll
  for (int off = 32; off; off >>= 1) sm += __shfl_xor(sm, off);
  if ((t & 63) == 0) rs[t >> 6] = sm;
  __syncthreads();
  float inv = 1.f / (rs[0] + rs[1] + rs[2] + rs[3]);
  float a0 = e0 * inv, a1 = e1 * inv;
  attw[(size_t)bh * S + t] = a0;
  attw[(size_t)bh * S + t + 256] = a1;
  att_out[((size_t)b * S + t) * H + h] = a0;
  att_out[((size_t)b * S + t + 256) * H + h] = a1;
}

// ---------------- MFMA GEMM core: LDS-FREE direct global->VGPR operand loads.
// Block 128x128, 4 waves (2x2), wave tile 64x64. With Bt in [N][K], both MFMA
// fragments are contiguous 16B/lane: lane l -> row base+(l&15), k (l>>4)*8.
// No barriers; latency hidden by TLP; L2 carries cross-wave operand re-reads.
template <int KD>
__device__ __forceinline__ void gemm_reg(const unsigned short* __restrict__ A,
                                         const unsigned short* __restrict__ Bt,
                                         int lda, int ldb, int m0, int n0, v4f acc[4][4]) {
  const int t = threadIdx.x;
  const int l = t & 63, w = t >> 6;
  const int wr = w >> 1, wc = w & 1;
  const int r15 = l & 15, g4 = l >> 4;
  const unsigned short* ap = A + (size_t)(m0 + wr * 64 + r15) * lda + g4 * 8;
  const unsigned short* bp = Bt + (size_t)(n0 + wc * 64 + r15) * ldb + g4 * 8;
#pragma unroll 2
  for (int kt = 0; kt < KD / 32; ++kt) {
    v8s af[4], bf[4];
#pragma unroll
    for (int i = 0; i < 4; ++i) af[i] = *(const v8s*)(ap + (size_t)i * 16 * lda + kt * 32);
#pragma unroll
    for (int j = 0; j < 4; ++j) bf[j] = *(const v8s*)(bp + (size_t)j * 16 * ldb + kt * 32);
#pragma unroll
    for (int i = 0; i < 4; ++i)
#pragma unroll
      for (int j = 0; j < 4; ++j)
        acc[i][j] = __builtin_amdgcn_mfma_f32_16x16x32_bf16(af[i], bf[j], acc[i][j], 0, 0, 0);
  }
}

// V-projection GEMM: vb[(b,s)][h*64+p] = bf16((xb @ wv)*attw); sqnorm[h] += sum o^2
__global__ __launch_bounds__(256) void k_gemm_v(const unsigned short* __restrict__ xb,
                                                const unsigned short* __restrict__ wvt,
                                                const float* __restrict__ attw,
                                                unsigned short* __restrict__ vb,
                                                float* __restrict__ sqnorm) {
  int m0 = blockIdx.x * 128, n0 = blockIdx.y * 128;
  v4f acc[4][4] = {};
  gemm_reg<512>(xb, wvt, 512, 512, m0, n0, acc);
  int t = threadIdx.x, l = t & 63, w = t >> 6, wr = w >> 1, wc = w & 1;
  int h = blockIdx.y * 2 + wc;
  float ssq = 0.f;
#pragma unroll
  for (int i = 0; i < 4; ++i) {
#pragma unroll
    for (int q = 0; q < 4; ++q) {
      int row = m0 + wr * 64 + i * 16 + (l >> 4) * 4 + q;
      int b = row >> 9, s = row & 511;
      float aw = attw[(size_t)(b * 8 + h) * 512 + s];
#pragma unroll
      for (int j = 0; j < 4; ++j) {
        int gc = n0 + wc * 64 + j * 16 + (l & 15);
        float o = acc[i][j][q] * aw;
        ssq += o * o;
        vb[(size_t)row * 512 + gc] = f2bf(o);
      }
    }
  }
#pragma unroll
  for (int off = 32; off; off >>= 1) ssq += __shfl_xor(ssq, off);
  if (l == 0) atomicAdd(&sqnorm[h], ssq);
}

// LN0 (wave per row, IN-PLACE over xb): xh := bf16(LN(perm(vb)*hs + xh))
__global__ __launch_bounds__(256) void k_ln0(const unsigned short* __restrict__ vb,
                                             unsigned short* xh,
                                             const float* __restrict__ sqnorm, const float* __restrict__ g,
                                             const float* __restrict__ bb) {
  __shared__ unsigned short perm[4][512];
  int t = threadIdx.x, w = t >> 6, l = t & 63;
  int r = blockIdx.x * 4 + w;
  *(v8s*)&perm[w][l * 8] = *(const v8s*)(vb + (size_t)r * 512 + l * 8);
  __syncthreads();
  v8s xv = *(const v8s*)(xh + (size_t)r * 512 + l * 8);
  float v[8];
#pragma unroll
  for (int j = 0; j < 8; ++j) {
    float hs = rsqrtf(fmaxf(sqnorm[j], 1e-12f));
    v[j] = bf2f(perm[w][j * 64 + l]) * hs + bf2f((unsigned short)xv[j]);
  }
  float sum = 0.f, sq = 0.f;
#pragma unroll
  for (int j = 0; j < 8; ++j) { sum += v[j]; sq += v[j] * v[j]; }
#pragma unroll
  for (int off = 32; off; off >>= 1) {
    sum += __shfl_xor(sum, off);
    sq += __shfl_xor(sq, off);
  }
  float mean = sum * (1.f / E);
  float var = fmaxf(sq * (1.f / E) - mean * mean, 0.f);
  float rstd = rsqrtf(var + 1e-3f);
  float4 g0 = *(const float4*)(g + l * 8), g1 = *(const float4*)(g + l * 8 + 4);
  float4 b0 = *(const float4*)(bb + l * 8), b1 = *(const float4*)(bb + l * 8 + 4);
  float gg[8] = {g0.x, g0.y, g0.z, g0.w, g1.x, g1.y, g1.z, g1.w};
  float bbv[8] = {b0.x, b0.y, b0.z, b0.w, b1.x, b1.y, b1.z, b1.w};
  v8s hv;
#pragma unroll
  for (int j = 0; j < 8; ++j) hv[j] = (short)f2bf((v[j] - mean) * rstd * gg[j] + bbv[j]);
  *(v8s*)(xh + (size_t)r * 512 + l * 8) = hv;
}

// FFN1: p1 = bf16(leaky_relu(hb @ w1 + b1)); rsump[row][by*2+wc] = partial sumsq
__global__ __launch_bounds__(256) void k_ffn1(const unsigned short* __restrict__ hb,
                                              const unsigned short* __restrict__ w1t,
                                              const float* __restrict__ b1, unsigned short* __restrict__ p1,
                                              float* __restrict__ rsump) {
  int m0 = blockIdx.x * 128, n0 = blockIdx.y * 128;
  v4f acc[4][4] = {};
  gemm_reg<512>(hb, w1t, 512, 512, m0, n0, acc);
  int t = threadIdx.x, l = t & 63, w = t >> 6, wr = w >> 1, wc = w & 1;
  int colb = n0 + wc * 64 + (l & 15);
  float bias[4];
#pragma unroll
  for (int j = 0; j < 4; ++j) bias[j] = b1[colb + j * 16];
#pragma unroll
  for (int i = 0; i < 4; ++i) {
#pragma unroll
    for (int q = 0; q < 4; ++q) {
      int row = m0 + wr * 64 + i * 16 + (l >> 4) * 4 + q;
      float ps = 0.f;
#pragma unroll
      for (int j = 0; j < 4; ++j) {
        float v = acc[i][j][q] + bias[j];
        v = v > 0.f ? v : 0.2f * v;
        ps += v * v;
        p1[(size_t)row * FF + colb + j * 16] = f2bf(v);
      }
#pragma unroll
      for (int m = 1; m < 16; m <<= 1) ps += __shfl_xor(ps, m);
      if ((l & 15) == 0) rsump[(size_t)row * 24 + blockIdx.y * 2 + wc] = ps;
    }
  }
}

// FFN2: p2b = bf16((p1 @ w2)*rinv + b2 + hb); rinv computed in-block from rsump
__global__ __launch_bounds__(256) void k_ffn2(const unsigned short* __restrict__ p1,
                                              const unsigned short* __restrict__ w2t,
                                              const float* __restrict__ rsump, const float* __restrict__ b2,
                                              const unsigned short* __restrict__ hb,
                                              unsigned short* __restrict__ p2b) {
  __shared__ float rinv_l[128];
  int m0 = blockIdx.x * 128, n0 = blockIdx.y * 128;
  int t = threadIdx.x;
  if (t < 128) {
    float s = 0.f;
#pragma unroll
    for (int k = 0; k < 24; ++k) s += rsump[(size_t)(m0 + t) * 24 + k];
    rinv_l[t] = rsqrtf(fmaxf(s, 1e-12f));
  }
  v4f acc[4][4] = {};
  gemm_reg<1536>(p1, w2t, 1536, 1536, m0, n0, acc);
  __syncthreads();
  int l = t & 63, w = t >> 6, wr = w >> 1, wc = w & 1;
  int colb = n0 + wc * 64 + (l & 15);
  float bias[4];
#pragma unroll
  for (int j = 0; j < 4; ++j) bias[j] = b2[colb + j * 16];
#pragma unroll
  for (int i = 0; i < 4; ++i) {
#pragma unroll
    for (int q = 0; q < 4; ++q) {
      int row = m0 + wr * 64 + i * 16 + (l >> 4) * 4 + q;
      float rv = rinv_l[row - m0];
#pragma unroll
      for (int j = 0; j < 4; ++j) {
        size_t idx = (size_t)row * 512 + colb + j * 16;
        float o = acc[i][j][q] * rv + bias[j] + bf2f(hb[idx]);
        p2b[idx] = f2bf(o);
      }
    }
  }
}

// LN1 (wave per row): out = LN(p2b)
__global__ __launch_bounds__(256) void k_ln1(const unsigned short* __restrict__ p2b, const float* __restrict__ g,
                                             const float* __restrict__ bb, float* __restrict__ outp) {
  int t = threadIdx.x, w = t >> 6, l = t & 63;
  int r = blockIdx.x * 4 + w;
  v8s pv = *(const v8s*)(p2b + (size_t)r * 512 + l * 8);
  float v[8];
#pragma unroll
  for (int j = 0; j < 8; ++j) v[j] = bf2f((unsigned short)pv[j]);
  float sum = 0.f, sq = 0.f;
#pragma unroll
  for (int j = 0; j < 8; ++j) { sum += v[j]; sq += v[j] * v[j]; }
#pragma unroll
  for (int off = 32; off; off >>= 1) {
    sum += __shfl_xor(sum, off);
    sq += __shfl_xor(sq, off);
  }
  float mean = sum * (1.f / E);
  float var = fmaxf(sq * (1.f / E) - mean * mean, 0.f);
  float rstd = rsqrtf(var + 1e-3f);
  float4 g0 = *(const float4*)(g + l * 8), g1 = *(const float4*)(g + l * 8 + 4);
  float4 b0 = *(const float4*)(bb + l * 8), b1 = *(const float4*)(bb + l * 8 + 4);
  float gg[8] = {g0.x, g0.y, g0.z, g0.w, g1.x, g1.y, g1.z, g1.w};
  float bbv[8] = {b0.x, b0.y, b0.z, b0.w, b1.x, b1.y, b1.z, b1.w};
  float4 o0, o1;
  o0.x = (v[0] - mean) * rstd * gg[0] + bbv[0];
  o0.y = (v[1] - mean) * rstd * gg[1] + bbv[1];
  o0.z = (v[2] - mean) * rstd * gg[2] + bbv[2];
  o0.w = (v[3] - mean) * rstd * gg[3] + bbv[3];
  o1.x = (v[4] - mean) * rstd * gg[4] + bbv[4];
  o1.y = (v[5] - mean) * rstd * gg[5] + bbv[5];
  o1.z = (v[6] - mean) * rstd * gg[6] + bbv[6];
  o1.w = (v[7] - mean) * rstd * gg[7] + bbv[7];
  *(float4*)(outp + (size_t)r * 512 + l * 8) = o0;
  *(float4*)(outp + (size_t)r * 512 + l * 8 + 4) = o1;
}

}  // namespace

extern "C" void kernel_launch(void* const* d_in, const int* in_sizes, int n_in,
                              void* d_out, int out_size, void* d_ws, size_t ws_size,
                              hipStream_t stream) {
  const float* x = (const float*)d_in[0];
  const float* wq = (const float*)d_in[1];
  const float* wk = (const float*)d_in[2];
  const float* wv = (const float*)d_in[3];
  const float* ln0_g = (const float*)d_in[4];
  const float* ln0_b = (const float*)d_in[5];
  const float* w1 = (const float*)d_in[6];
  const float* b1 = (const float*)d_in[7];
  const float* w2 = (const float*)d_in[8];
  const float* b2 = (const float*)d_in[9];
  const float* ln1_g = (const float*)d_in[10];
  const float* ln1_b = (const float*)d_in[11];

  float* att_out = (float*)d_out;                  // [B,S,H]
  float* outp = (float*)d_out + (size_t)B * S * H; // [B,S,E]

  char* ws = (char*)d_ws;
  float* xsump = (float*)(ws + 0);                        // 1 MB  [B][16][E]
  float* wqkb = (float*)(ws + 1048576);                   // 512 KB
  float* scores = (float*)(ws + 1572864);                 // 512 KB
  float* attw = (float*)(ws + 2097152);                   // 512 KB
  float* sqnorm = (float*)(ws + 2621440);                 // 4 KB (pad)
  float* rsump = (float*)(ws + 2625536);                  // 1.5 MB [BS][24]
  unsigned short* w1t = (unsigned short*)(ws + 4263936);  // 1.5 MB [FF][E]
  unsigned short* w2t = (unsigned short*)(ws + 5836800);  // 1.5 MB [E][FF]
  unsigned short* wvt = (unsigned short*)(ws + 7409664);  // 512 KB [H*P][E]
  unsigned short* xb = (unsigned short*)(ws + 7933952);   // 16 MB [BS][E] bf16 (hb aliases after ln0)
  unsigned short* vb = (unsigned short*)(ws + 24711168);  // 16 MB [BS][512] bf16 (p2b aliases)
  unsigned short* p1 = (unsigned short*)(ws + 41488384);  // 48 MB [BS][FF] bf16
  unsigned short* hb = xb;                                // ln0 writes in place
  unsigned short* p2b = vb;                               // vb dead after ln0

  k_prep<<<704, 256, 0, stream>>>(w1, w2, wv, x, w1t, w2t, wvt, xb, xsump);
  k_wqk<<<dim3(B, H), 256, 0, stream>>>(xsump, wq, wk, wqkb, sqnorm);
  k_scores<<<dim3(B, S / 64), 256, 0, stream>>>(xb, wqkb, scores);
  k_softmax<<<B * H, 256, 0, stream>>>(scores, attw, att_out);
  k_gemm_v<<<dim3(BS / 128, 4), 256, 0, stream>>>(xb, wvt, attw, vb, sqnorm);
  k_ln0<<<BS / 4, 256, 0, stream>>>(vb, xb, sqnorm, ln0_g, ln0_b);
  k_ffn1<<<dim3(BS / 128, FF / 128), 256, 0, stream>>>(hb, w1t, b1, p1, rsump);
  k_ffn2<<<dim3(BS / 128, E / 128), 256, 0, stream>>>(p1, w2t, rsump, b2, hb, p2b);
  k_ln1<<<BS / 4, 256, 0, stream>>>(p2b, ln1_g, ln1_b, outp);
}

// Round 9
// 227.302 us; speedup vs baseline: 1.3451x; 1.3451x over previous
//
#include <hip/hip_runtime.h>
#include <hip/hip_bf16.h>

namespace {

constexpr int B = 32, S = 512, E = 512, H = 8, P = 64, FF = 1536;
constexpr int BS = B * S;

typedef short v8s __attribute__((ext_vector_type(8)));
typedef float v4f __attribute__((ext_vector_type(4)));

__device__ __forceinline__ float bf2f(unsigned short u) {
  return __uint_as_float(((unsigned int)u) << 16);
}
__device__ __forceinline__ unsigned short f2bf(float f) {
  __hip_bfloat16 h = __float2bfloat16(f);
  return *reinterpret_cast<unsigned short*>(&h);
}

__device__ __forceinline__ void gl_lds16(const unsigned short* g, unsigned short* l) {
  __builtin_amdgcn_global_load_lds((const __attribute__((address_space(1))) unsigned int*)g,
                                   (__attribute__((address_space(3))) unsigned int*)l, 16, 0, 0);
}

// ---------------- prep: weight transposes (blocks 0..447) + x->bf16/colsum (448..703) ----
__global__ __launch_bounds__(256) void k_prep(const float* __restrict__ w1, const float* __restrict__ w2,
                                              const float* __restrict__ wv, const float* __restrict__ x,
                                              unsigned short* __restrict__ w1t, unsigned short* __restrict__ w2t,
                                              unsigned short* __restrict__ wvt, unsigned short* __restrict__ xb,
                                              float* __restrict__ xsump) {
  __shared__ float tile[64][65];
  int id = blockIdx.x;
  int t = threadIdx.x;
  if (id >= 448) {
    int i = id - 448;
    int b = i >> 3, ch = i & 7;
    int c4 = (t & 127) * 4;
    int rh = t >> 7;
    const float* xp = x + ((size_t)b * S + ch * 64 + rh * 32) * E;
    unsigned short* xbp = xb + ((size_t)b * S + ch * 64 + rh * 32) * E;
    float ax = 0.f, ay = 0.f, az = 0.f, aw = 0.f;
    for (int s = 0; s < 32; ++s) {
      float4 v = *(const float4*)(xp + (size_t)s * E + c4);
      ax += v.x; ay += v.y; az += v.z; aw += v.w;
      ushort4 u;
      u.x = f2bf(v.x); u.y = f2bf(v.y); u.z = f2bf(v.z); u.w = f2bf(v.w);
      *(ushort4*)(xbp + (size_t)s * E + c4) = u;
    }
    float* xs = xsump + ((size_t)b * 16 + ch * 2 + rh) * E + c4;
    xs[0] = ax; xs[1] = ay; xs[2] = az; xs[3] = aw;
    return;
  }
  const float* inp;
  unsigned short* outp;
  int R, C, bx, by;
  size_t zo = 0;
  if (id < 192) {
    inp = w1; outp = w1t; R = 512; C = 1536; bx = id % 24; by = id / 24;
  } else if (id < 384) {
    int i = id - 192;
    inp = w2; outp = w2t; R = 1536; C = 512; bx = i & 7; by = i >> 3;
  } else {
    int i = id - 384;
    inp = wv; outp = wvt; R = 512; C = 64; bx = 0; by = i & 7; zo = (size_t)(i >> 3) * (512 * 64);
  }
  int c0 = bx * 64, r0 = by * 64;
#pragma unroll
  for (int j = 0; j < 4; ++j) {
    int i = t + j * 256;
    int rr = i >> 4, c4 = i & 15;
    float4 v = *(const float4*)(inp + zo + (size_t)(r0 + rr) * C + c0 + c4 * 4);
    tile[rr][c4 * 4 + 0] = v.x;
    tile[rr][c4 * 4 + 1] = v.y;
    tile[rr][c4 * 4 + 2] = v.z;
    tile[rr][c4 * 4 + 3] = v.w;
  }
  __syncthreads();
#pragma unroll
  for (int j = 0; j < 4; ++j) {
    int u = t + j * 256;
    int cr = u >> 4, q = u & 15;
    ushort4 o;
    o.x = f2bf(tile[q * 4 + 0][cr]);
    o.y = f2bf(tile[q * 4 + 1][cr]);
    o.z = f2bf(tile[q * 4 + 2][cr]);
    o.w = f2bf(tile[q * 4 + 3][cr]);
    *(ushort4*)(outp + zo + (size_t)(c0 + cr) * R + r0 + q * 4) = o;
  }
}

// ksum[p]=sum_e xsum[b,e]*wk[h,e,p]; wqk[b,h,e]=0.125*sum_p wq[h,e,p]*ksum[p]; zero sqnorm
__global__ __launch_bounds__(256) void k_wqk(const float* __restrict__ xsump, const float* __restrict__ wq,
                                             const float* __restrict__ wk, float* __restrict__ wqk,
                                             float* __restrict__ sqnorm) {
  int b = blockIdx.x, h = blockIdx.y, t = threadIdx.x;
  if (b == 0 && h == 0 && t < 8) sqnorm[t] = 0.f;
  __shared__ float xsl[E];
  __shared__ float ksp[4][64];
  __shared__ float ks[64];
#pragma unroll
  for (int j = 0; j < 2; ++j) {
    int e = t + j * 256;
    float s = 0.f;
#pragma unroll
    for (int c = 0; c < 16; ++c) s += xsump[((size_t)b * 16 + c) * E + e];
    xsl[e] = s;
  }
  __syncthreads();
  {
    const float* wkh = wk + (size_t)h * E * P;
    int p = t & 63, ec = t >> 6;
    float a = 0.f;
    for (int e = ec * 128; e < ec * 128 + 128; ++e) a += xsl[e] * wkh[e * 64 + p];
    ksp[ec][p] = a;
  }
  __syncthreads();
  if (t < 64) ks[t] = ksp[0][t] + ksp[1][t] + ksp[2][t] + ksp[3][t];
  __syncthreads();
  const float* wqh = wq + (size_t)h * E * P;
#pragma unroll
  for (int j = 0; j < 2; ++j) {
    int e = t + j * 256;
    float a = 0.f;
#pragma unroll 8
    for (int pp = 0; pp < P; ++pp) a += wqh[e * 64 + pp] * ks[pp];
    wqk[((size_t)b * H + h) * E + e] = a * 0.125f;
  }
}

// scores[b,h,s] = xb[b,s,:] . wqk[b,h,:]
__global__ __launch_bounds__(256) void k_scores(const unsigned short* __restrict__ xb,
                                                const float* __restrict__ wqk, float* __restrict__ scores) {
  int b = blockIdx.x, s0 = blockIdx.y * 64, t = threadIdx.x;
  __shared__ float xs[64][68];
  __shared__ float wt[8][68];
  float acc[2] = {0.f, 0.f};
  for (int ec = 0; ec < E; ec += 64) {
    {
      int row = t >> 2, cg = (t & 3) * 16;
      v8s v0 = *(const v8s*)(xb + ((size_t)b * S + s0 + row) * E + ec + cg);
      v8s v1 = *(const v8s*)(xb + ((size_t)b * S + s0 + row) * E + ec + cg + 8);
      float4 f0, f1, f2, f3;
      f0.x = bf2f((unsigned short)v0[0]); f0.y = bf2f((unsigned short)v0[1]);
      f0.z = bf2f((unsigned short)v0[2]); f0.w = bf2f((unsigned short)v0[3]);
      f1.x = bf2f((unsigned short)v0[4]); f1.y = bf2f((unsigned short)v0[5]);
      f1.z = bf2f((unsigned short)v0[6]); f1.w = bf2f((unsigned short)v0[7]);
      f2.x = bf2f((unsigned short)v1[0]); f2.y = bf2f((unsigned short)v1[1]);
      f2.z = bf2f((unsigned short)v1[2]); f2.w = bf2f((unsigned short)v1[3]);
      f3.x = bf2f((unsigned short)v1[4]); f3.y = bf2f((unsigned short)v1[5]);
      f3.z = bf2f((unsigned short)v1[6]); f3.w = bf2f((unsigned short)v1[7]);
      *(float4*)&xs[row][cg] = f0;
      *(float4*)&xs[row][cg + 4] = f1;
      *(float4*)&xs[row][cg + 8] = f2;
      *(float4*)&xs[row][cg + 12] = f3;
    }
    if (t < 128) {
      int hr = t >> 4, c4 = t & 15;
      float4 v = *(const float4*)(wqk + ((size_t)b * H + hr) * E + ec + c4 * 4);
      *(float4*)&wt[hr][c4 * 4] = v;
    }
    __syncthreads();
#pragma unroll
    for (int j = 0; j < 2; ++j) {
      int o = t + j * 256;
      int sl = o >> 3, hh = o & 7;
      float a = 0.f;
#pragma unroll
      for (int c4 = 0; c4 < 16; ++c4) {
        float4 xa = *(const float4*)&xs[sl][c4 * 4];
        float4 wa = *(const float4*)&wt[hh][c4 * 4];
        a += xa.x * wa.x + xa.y * wa.y + xa.z * wa.z + xa.w * wa.w;
      }
      acc[j] += a;
    }
    __syncthreads();
  }
#pragma unroll
  for (int j = 0; j < 2; ++j) {
    int o = t + j * 256;
    int sl = o >> 3, hh = o & 7;
    scores[((size_t)b * H + hh) * S + s0 + sl] = acc[j];
  }
}

__global__ __launch_bounds__(256) void k_softmax(const float* __restrict__ scores, float* __restrict__ attw,
                                                 float* __restrict__ att_out) {
  int bh = blockIdx.x, t = threadIdx.x;
  int b = bh >> 3, h = bh & 7;
  float v0 = scores[(size_t)bh * S + t];
  float v1 = scores[(size_t)bh * S + t + 256];
  float m = fmaxf(v0, v1);
#pragma unroll
  for (int off = 32; off; off >>= 1) m = fmaxf(m, __shfl_xor(m, off));
  __shared__ float rm[4], rs[4];
  if ((t & 63) == 0) rm[t >> 6] = m;
  __syncthreads();
  m = fmaxf(fmaxf(rm[0], rm[1]), fmaxf(rm[2], rm[3]));
  float e0 = __expf(v0 - m), e1 = __expf(v1 - m);
  float sm = e0 + e1;
#pragma unroll
  for (int off = 32; off; off >>= 1) sm += __shfl_xor(sm, off);
  if ((t & 63) == 0) rs[t >> 6] = sm;
  __syncthreads();
  float inv = 1.f / (rs[0] + rs[1] + rs[2] + rs[3]);
  float a0 = e0 * inv, a1 = e1 * inv;
  attw[(size_t)bh * S + t] = a0;
  attw[(size_t)bh * S + t + 256] = a1;
  att_out[((size_t)b * S + t) * H + h] = a0;
  att_out[((size_t)b * S + t + 256) * H + h] = a1;
}

// ---------------- HYBRID GEMM core: A operand direct global->VGPR (lane-contiguous
// 16B fragments, proven r8), B staged via global_load_lds. Halves LDS pipe traffic
// vs full-LDS core; keeps r3's proven barrier pacing (barrier drain covers A too).
// Block 128x128, 4 waves 2x2, BK=32, single 8KB B buffer.
template <int KD>
__device__ __forceinline__ void gemm_hyb(const unsigned short* __restrict__ A,
                                         const unsigned short* __restrict__ Bt,
                                         int lda, int ldb, int m0, int n0,
                                         unsigned short* Bs, v4f acc[4][4]) {
  const int t = threadIdx.x;
  const int l = t & 63, w = t >> 6;
  const int wr = w >> 1, wc = w & 1;
  const int r15 = l & 15, g4 = l >> 4;
  const unsigned short* ap = A + (size_t)(m0 + wr * 64 + r15) * lda + g4 * 8;
  for (int kt = 0; kt < KD / 32; ++kt) {
    const int col = kt * 32;
    v8s af[4];
#pragma unroll
    for (int i = 0; i < 4; ++i) af[i] = *(const v8s*)(ap + (size_t)(i * 16) * lda + col);
#pragma unroll
    for (int cc = 0; cc < 2; ++cc) {
      int c = w * 2 + cc;  // B chunk: 16 rows x 32 k (1KB), slot = lane identity
      gl_lds16(Bt + (size_t)(n0 + c * 16 + r15) * ldb + col + g4 * 8, Bs + c * 512);
    }
    __syncthreads();  // drains vmcnt(0): A frags + B stage both complete
    v8s bf[4];
#pragma unroll
    for (int j = 0; j < 4; ++j) bf[j] = *(const v8s*)(Bs + (wc * 4 + j) * 512 + l * 8);
    __builtin_amdgcn_s_setprio(1);
#pragma unroll
    for (int i = 0; i < 4; ++i)
#pragma unroll
      for (int j = 0; j < 4; ++j)
        acc[i][j] = __builtin_amdgcn_mfma_f32_16x16x32_bf16(af[i], bf[j], acc[i][j], 0, 0, 0);
    __builtin_amdgcn_s_setprio(0);
    __syncthreads();  // B buffer reads done before next stage
  }
}

// ---------------- r3-verbatim full-LDS core (44.7us config) for ffn2 A/B reference ----
template <int KD>
__device__ __forceinline__ void gemm_tile_gl(const unsigned short* __restrict__ A,
                                             const unsigned short* __restrict__ Bt,
                                             int lda, int ldb, int m0, int n0,
                                             unsigned short* As, unsigned short* Bs, v4f acc[4][4]) {
  const int t = threadIdx.x;
  const int l = t & 63, w = t >> 6;
  const int wr = w >> 1, wc = w & 1;
  const int lr = l >> 2, lg = l & 3;
  const int ch = l >> 4, r15 = l & 15;
  for (int kc = 0; kc < KD; kc += 32) {
#pragma unroll
    for (int cc = 0; cc < 2; ++cc) {
      int c = w * 2 + cc;
      int row = c * 16 + lr;
      int sg = lg ^ ((row >> 1) & 3);  // inverse-swizzled source granule
      const unsigned short* ga = A + (size_t)(m0 + row) * lda + kc + sg * 8;
      const unsigned short* gb = Bt + (size_t)(n0 + row) * ldb + kc + sg * 8;
      gl_lds16(ga, As + c * 512);
      gl_lds16(gb, Bs + c * 512);
    }
    __syncthreads();
    v8s af[4], bfr[4];
#pragma unroll
    for (int i = 0; i < 4; ++i) {
      int ra = wr * 64 + i * 16 + r15;
      af[i] = *(const v8s*)(As + ra * 32 + (ch ^ ((ra >> 1) & 3)) * 8);
      int rb = wc * 64 + i * 16 + r15;
      bfr[i] = *(const v8s*)(Bs + rb * 32 + (ch ^ ((rb >> 1) & 3)) * 8);
    }
#pragma unroll
    for (int i = 0; i < 4; ++i)
#pragma unroll
      for (int j = 0; j < 4; ++j)
        acc[i][j] = __builtin_amdgcn_mfma_f32_16x16x32_bf16(af[i], bfr[j], acc[i][j], 0, 0, 0);
    __syncthreads();
  }
}

// V-projection GEMM (hybrid): vb = bf16((xb @ wv)*attw); sqnorm[h] += sum o^2
__global__ __launch_bounds__(256) void k_gemm_v(const unsigned short* __restrict__ xb,
                                                const unsigned short* __restrict__ wvt,
                                                const float* __restrict__ attw,
                                                unsigned short* __restrict__ vb,
                                                float* __restrict__ sqnorm) {
  __shared__ alignas(16) unsigned short Bs[4096];
  int m0 = blockIdx.x * 128, n0 = blockIdx.y * 128;
  v4f acc[4][4] = {};
  gemm_hyb<512>(xb, wvt, 512, 512, m0, n0, Bs, acc);
  int t = threadIdx.x, l = t & 63, w = t >> 6, wr = w >> 1, wc = w & 1;
  int h = blockIdx.y * 2 + wc;
  float ssq = 0.f;
#pragma unroll
  for (int i = 0; i < 4; ++i) {
#pragma unroll
    for (int q = 0; q < 4; ++q) {
      int row = m0 + wr * 64 + i * 16 + (l >> 4) * 4 + q;
      int b = row >> 9, s = row & 511;
      float aw = attw[(size_t)(b * 8 + h) * 512 + s];
#pragma unroll
      for (int j = 0; j < 4; ++j) {
        int gc = n0 + wc * 64 + j * 16 + (l & 15);
        float o = acc[i][j][q] * aw;
        ssq += o * o;
        vb[(size_t)row * 512 + gc] = f2bf(o);
      }
    }
  }
#pragma unroll
  for (int off = 32; off; off >>= 1) ssq += __shfl_xor(ssq, off);
  if (l == 0) atomicAdd(&sqnorm[h], ssq);
}

// LN0 (wave per row, IN-PLACE over xb): xh := bf16(LN(perm(vb)*hs + xh))
__global__ __launch_bounds__(256) void k_ln0(const unsigned short* __restrict__ vb,
                                             unsigned short* xh,
                                             const float* __restrict__ sqnorm, const float* __restrict__ g,
                                             const float* __restrict__ bb) {
  __shared__ unsigned short perm[4][512];
  int t = threadIdx.x, w = t >> 6, l = t & 63;
  int r = blockIdx.x * 4 + w;
  *(v8s*)&perm[w][l * 8] = *(const v8s*)(vb + (size_t)r * 512 + l * 8);
  __syncthreads();
  v8s xv = *(const v8s*)(xh + (size_t)r * 512 + l * 8);
  float v[8];
#pragma unroll
  for (int j = 0; j < 8; ++j) {
    float hs = rsqrtf(fmaxf(sqnorm[j], 1e-12f));
    v[j] = bf2f(perm[w][j * 64 + l]) * hs + bf2f((unsigned short)xv[j]);
  }
  float sum = 0.f, sq = 0.f;
#pragma unroll
  for (int j = 0; j < 8; ++j) { sum += v[j]; sq += v[j] * v[j]; }
#pragma unroll
  for (int off = 32; off; off >>= 1) {
    sum += __shfl_xor(sum, off);
    sq += __shfl_xor(sq, off);
  }
  float mean = sum * (1.f / E);
  float var = fmaxf(sq * (1.f / E) - mean * mean, 0.f);
  float rstd = rsqrtf(var + 1e-3f);
  float4 g0 = *(const float4*)(g + l * 8), g1 = *(const float4*)(g + l * 8 + 4);
  float4 b0 = *(const float4*)(bb + l * 8), b1 = *(const float4*)(bb + l * 8 + 4);
  float gg[8] = {g0.x, g0.y, g0.z, g0.w, g1.x, g1.y, g1.z, g1.w};
  float bbv[8] = {b0.x, b0.y, b0.z, b0.w, b1.x, b1.y, b1.z, b1.w};
  v8s hv;
#pragma unroll
  for (int j = 0; j < 8; ++j) hv[j] = (short)f2bf((v[j] - mean) * rstd * gg[j] + bbv[j]);
  *(v8s*)(xh + (size_t)r * 512 + l * 8) = hv;
}

// FFN1 (hybrid): p1 = bf16(leaky_relu(hb @ w1 + b1)); rsump partial sumsq
__global__ __launch_bounds__(256) void k_ffn1(const unsigned short* __restrict__ hb,
                                              const unsigned short* __restrict__ w1t,
                                              const float* __restrict__ b1, unsigned short* __restrict__ p1,
                                              float* __restrict__ rsump) {
  __shared__ alignas(16) unsigned short Bs[4096];
  int m0 = blockIdx.x * 128, n0 = blockIdx.y * 128;
  v4f acc[4][4] = {};
  gemm_hyb<512>(hb, w1t, 512, 512, m0, n0, Bs, acc);
  int t = threadIdx.x, l = t & 63, w = t >> 6, wr = w >> 1, wc = w & 1;
  int colb = n0 + wc * 64 + (l & 15);
  float bias[4];
#pragma unroll
  for (int j = 0; j < 4; ++j) bias[j] = b1[colb + j * 16];
#pragma unroll
  for (int i = 0; i < 4; ++i) {
#pragma unroll
    for (int q = 0; q < 4; ++q) {
      int row = m0 + wr * 64 + i * 16 + (l >> 4) * 4 + q;
      float ps = 0.f;
#pragma unroll
      for (int j = 0; j < 4; ++j) {
        float v = acc[i][j][q] + bias[j];
        v = v > 0.f ? v : 0.2f * v;
        ps += v * v;
        p1[(size_t)row * FF + colb + j * 16] = f2bf(v);
      }
#pragma unroll
      for (int m = 1; m < 16; m <<= 1) ps += __shfl_xor(ps, m);
      if ((l & 15) == 0) rsump[(size_t)row * 24 + blockIdx.y * 2 + wc] = ps;
    }
  }
}

// FFN2 (r3-verbatim full-LDS core): p2b = bf16((p1 @ w2)*rinv + b2 + hb)
__global__ __launch_bounds__(256) void k_ffn2(const unsigned short* __restrict__ p1,
                                              const unsigned short* __restrict__ w2t,
                                              const float* __restrict__ rsump, const float* __restrict__ b2,
                                              const unsigned short* __restrict__ hb,
                                              unsigned short* __restrict__ p2b) {
  __shared__ alignas(16) unsigned short As[4096], Bs[4096];
  __shared__ float rinv_l[128];
  int m0 = blockIdx.x * 128, n0 = blockIdx.y * 128;
  int t = threadIdx.x;
  if (t < 128) {
    float s = 0.f;
#pragma unroll
    for (int k = 0; k < 24; ++k) s += rsump[(size_t)(m0 + t) * 24 + k];
    rinv_l[t] = rsqrtf(fmaxf(s, 1e-12f));
  }
  v4f acc[4][4] = {};
  gemm_tile_gl<1536>(p1, w2t, 1536, 1536, m0, n0, As, Bs, acc);
  int l = t & 63, w = t >> 6, wr = w >> 1, wc = w & 1;
  int colb = n0 + wc * 64 + (l & 15);
  float bias[4];
#pragma unroll
  for (int j = 0; j < 4; ++j) bias[j] = b2[colb + j * 16];
#pragma unroll
  for (int i = 0; i < 4; ++i) {
#pragma unroll
    for (int q = 0; q < 4; ++q) {
      int row = m0 + wr * 64 + i * 16 + (l >> 4) * 4 + q;
      float rv = rinv_l[row - m0];
#pragma unroll
      for (int j = 0; j < 4; ++j) {
        size_t idx = (size_t)row * 512 + colb + j * 16;
        float o = acc[i][j][q] * rv + bias[j] + bf2f(hb[idx]);
        p2b[idx] = f2bf(o);
      }
    }
  }
}

// LN1 (wave per row): out = LN(p2b)
__global__ __launch_bounds__(256) void k_ln1(const unsigned short* __restrict__ p2b, const float* __restrict__ g,
                                             const float* __restrict__ bb, float* __restrict__ outp) {
  int t = threadIdx.x, w = t >> 6, l = t & 63;
  int r = blockIdx.x * 4 + w;
  v8s pv = *(const v8s*)(p2b + (size_t)r * 512 + l * 8);
  float v[8];
#pragma unroll
  for (int j = 0; j < 8; ++j) v[j] = bf2f((unsigned short)pv[j]);
  float sum = 0.f, sq = 0.f;
#pragma unroll
  for (int j = 0; j < 8; ++j) { sum += v[j]; sq += v[j] * v[j]; }
#pragma unroll
  for (int off = 32; off; off >>= 1) {
    sum += __shfl_xor(sum, off);
    sq += __shfl_xor(sq, off);
  }
  float mean = sum * (1.f / E);
  float var = fmaxf(sq * (1.f / E) - mean * mean, 0.f);
  float rstd = rsqrtf(var + 1e-3f);
  float4 g0 = *(const float4*)(g + l * 8), g1 = *(const float4*)(g + l * 8 + 4);
  float4 b0 = *(const float4*)(bb + l * 8), b1 = *(const float4*)(bb + l * 8 + 4);
  float gg[8] = {g0.x, g0.y, g0.z, g0.w, g1.x, g1.y, g1.z, g1.w};
  float bbv[8] = {b0.x, b0.y, b0.z, b0.w, b1.x, b1.y, b1.z, b1.w};
  float4 o0, o1;
  o0.x = (v[0] - mean) * rstd * gg[0] + bbv[0];
  o0.y = (v[1] - mean) * rstd * gg[1] + bbv[1];
  o0.z = (v[2] - mean) * rstd * gg[2] + bbv[2];
  o0.w = (v[3] - mean) * rstd * gg[3] + bbv[3];
  o1.x = (v[4] - mean) * rstd * gg[4] + bbv[4];
  o1.y = (v[5] - mean) * rstd * gg[5] + bbv[5];
  o1.z = (v[6] - mean) * rstd * gg[6] + bbv[6];
  o1.w = (v[7] - mean) * rstd * gg[7] + bbv[7];
  *(float4*)(outp + (size_t)r * 512 + l * 8) = o0;
  *(float4*)(outp + (size_t)r * 512 + l * 8 + 4) = o1;
}

}  // namespace

extern "C" void kernel_launch(void* const* d_in, const int* in_sizes, int n_in,
                              void* d_out, int out_size, void* d_ws, size_t ws_size,
                              hipStream_t stream) {
  const float* x = (const float*)d_in[0];
  const float* wq = (const float*)d_in[1];
  const float* wk = (const float*)d_in[2];
  const float* wv = (const float*)d_in[3];
  const float* ln0_g = (const float*)d_in[4];
  const float* ln0_b = (const float*)d_in[5];
  const float* w1 = (const float*)d_in[6];
  const float* b1 = (const float*)d_in[7];
  const float* w2 = (const float*)d_in[8];
  const float* b2 = (const float*)d_in[9];
  const float* ln1_g = (const float*)d_in[10];
  const float* ln1_b = (const float*)d_in[11];

  float* att_out = (float*)d_out;                  // [B,S,H]
  float* outp = (float*)d_out + (size_t)B * S * H; // [B,S,E]

  char* ws = (char*)d_ws;
  float* xsump = (float*)(ws + 0);                        // 1 MB  [B][16][E]
  float* wqkb = (float*)(ws + 1048576);                   // 512 KB
  float* scores = (float*)(ws + 1572864);                 // 512 KB
  float* attw = (float*)(ws + 2097152);                   // 512 KB
  float* sqnorm = (float*)(ws + 2621440);                 // 4 KB (pad)
  float* rsump = (float*)(ws + 2625536);                  // 1.5 MB [BS][24]
  unsigned short* w1t = (unsigned short*)(ws + 4263936);  // 1.5 MB [FF][E]
  unsigned short* w2t = (unsigned short*)(ws + 5836800);  // 1.5 MB [E][FF]
  unsigned short* wvt = (unsigned short*)(ws + 7409664);  // 512 KB [H*P][E]
  unsigned short* xb = (unsigned short*)(ws + 7933952);   // 16 MB [BS][E] bf16 (hb aliases after ln0)
  unsigned short* vb = (unsigned short*)(ws + 24711168);  // 16 MB [BS][512] bf16 (p2b aliases)
  unsigned short* p1 = (unsigned short*)(ws + 41488384);  // 48 MB [BS][FF] bf16
  unsigned short* hb = xb;                                // ln0 writes in place
  unsigned short* p2b = vb;                               // vb dead after ln0

  k_prep<<<704, 256, 0, stream>>>(w1, w2, wv, x, w1t, w2t, wvt, xb, xsump);
  k_wqk<<<dim3(B, H), 256, 0, stream>>>(xsump, wq, wk, wqkb, sqnorm);
  k_scores<<<dim3(B, S / 64), 256, 0, stream>>>(xb, wqkb, scores);
  k_softmax<<<B * H, 256, 0, stream>>>(scores, attw, att_out);
  k_gemm_v<<<dim3(BS / 128, 4), 256, 0, stream>>>(xb, wvt, attw, vb, sqnorm);
  k_ln0<<<BS / 4, 256, 0, stream>>>(vb, xb, sqnorm, ln0_g, ln0_b);
  k_ffn1<<<dim3(BS / 128, FF / 128), 256, 0, stream>>>(hb, w1t, b1, p1, rsump);
  k_ffn2<<<dim3(BS / 128, E / 128), 256, 0, stream>>>(p1, w2t, rsump, b2, hb, p2b);
  k_ln1<<<BS / 4, 256, 0, stream>>>(p2b, ln1_g, ln1_b, outp);
}

// Round 10
// 176.359 us; speedup vs baseline: 1.7337x; 1.2889x over previous
//
#include <hip/hip_runtime.h>
#include <hip/hip_bf16.h>

namespace {

constexpr int B = 32, S = 512, E = 512, H = 8, P = 64, FF = 1536;
constexpr int BS = B * S;

typedef short v8s __attribute__((ext_vector_type(8)));
typedef float v4f __attribute__((ext_vector_type(4)));

__device__ __forceinline__ float bf2f(unsigned short u) {
  return __uint_as_float(((unsigned int)u) << 16);
}
__device__ __forceinline__ unsigned short f2bf(float f) {
  __hip_bfloat16 h = __float2bfloat16(f);
  return *reinterpret_cast<unsigned short*>(&h);
}

__device__ __forceinline__ void gl_lds16(const unsigned short* g, unsigned short* l) {
  __builtin_amdgcn_global_load_lds((const __attribute__((address_space(1))) unsigned int*)g,
                                   (__attribute__((address_space(3))) unsigned int*)l, 16, 0, 0);
}

// ---------------- prep: weight transposes (blocks 0..447) + x->bf16/colsum (448..703) ----
__global__ __launch_bounds__(256) void k_prep(const float* __restrict__ w1, const float* __restrict__ w2,
                                              const float* __restrict__ wv, const float* __restrict__ x,
                                              unsigned short* __restrict__ w1t, unsigned short* __restrict__ w2t,
                                              unsigned short* __restrict__ wvt, unsigned short* __restrict__ xb,
                                              float* __restrict__ xsump) {
  __shared__ float tile[64][65];
  int id = blockIdx.x;
  int t = threadIdx.x;
  if (id >= 448) {
    int i = id - 448;
    int b = i >> 3, ch = i & 7;
    int c4 = (t & 127) * 4;
    int rh = t >> 7;
    const float* xp = x + ((size_t)b * S + ch * 64 + rh * 32) * E;
    unsigned short* xbp = xb + ((size_t)b * S + ch * 64 + rh * 32) * E;
    float ax = 0.f, ay = 0.f, az = 0.f, aw = 0.f;
    for (int s = 0; s < 32; ++s) {
      float4 v = *(const float4*)(xp + (size_t)s * E + c4);
      ax += v.x; ay += v.y; az += v.z; aw += v.w;
      ushort4 u;
      u.x = f2bf(v.x); u.y = f2bf(v.y); u.z = f2bf(v.z); u.w = f2bf(v.w);
      *(ushort4*)(xbp + (size_t)s * E + c4) = u;
    }
    float* xs = xsump + ((size_t)b * 16 + ch * 2 + rh) * E + c4;
    xs[0] = ax; xs[1] = ay; xs[2] = az; xs[3] = aw;
    return;
  }
  const float* inp;
  unsigned short* outp;
  int R, C, bx, by;
  size_t zo = 0;
  if (id < 192) {
    inp = w1; outp = w1t; R = 512; C = 1536; bx = id % 24; by = id / 24;
  } else if (id < 384) {
    int i = id - 192;
    inp = w2; outp = w2t; R = 1536; C = 512; bx = i & 7; by = i >> 3;
  } else {
    int i = id - 384;
    inp = wv; outp = wvt; R = 512; C = 64; bx = 0; by = i & 7; zo = (size_t)(i >> 3) * (512 * 64);
  }
  int c0 = bx * 64, r0 = by * 64;
#pragma unroll
  for (int j = 0; j < 4; ++j) {
    int i = t + j * 256;
    int rr = i >> 4, c4 = i & 15;
    float4 v = *(const float4*)(inp + zo + (size_t)(r0 + rr) * C + c0 + c4 * 4);
    tile[rr][c4 * 4 + 0] = v.x;
    tile[rr][c4 * 4 + 1] = v.y;
    tile[rr][c4 * 4 + 2] = v.z;
    tile[rr][c4 * 4 + 3] = v.w;
  }
  __syncthreads();
#pragma unroll
  for (int j = 0; j < 4; ++j) {
    int u = t + j * 256;
    int cr = u >> 4, q = u & 15;
    ushort4 o;
    o.x = f2bf(tile[q * 4 + 0][cr]);
    o.y = f2bf(tile[q * 4 + 1][cr]);
    o.z = f2bf(tile[q * 4 + 2][cr]);
    o.w = f2bf(tile[q * 4 + 3][cr]);
    *(ushort4*)(outp + zo + (size_t)(c0 + cr) * R + r0 + q * 4) = o;
  }
}

// ksum[p]=sum_e xsum[b,e]*wk[h,e,p]; wqk[b,h,e]=0.125*sum_p wq[h,e,p]*ksum[p]; zero sqnorm
__global__ __launch_bounds__(256) void k_wqk(const float* __restrict__ xsump, const float* __restrict__ wq,
                                             const float* __restrict__ wk, float* __restrict__ wqk,
                                             float* __restrict__ sqnorm) {
  int b = blockIdx.x, h = blockIdx.y, t = threadIdx.x;
  if (b == 0 && h == 0 && t < 8) sqnorm[t] = 0.f;
  __shared__ float xsl[E];
  __shared__ float ksp[4][64];
  __shared__ float ks[64];
#pragma unroll
  for (int j = 0; j < 2; ++j) {
    int e = t + j * 256;
    float s = 0.f;
#pragma unroll
    for (int c = 0; c < 16; ++c) s += xsump[((size_t)b * 16 + c) * E + e];
    xsl[e] = s;
  }
  __syncthreads();
  {
    const float* wkh = wk + (size_t)h * E * P;
    int p = t & 63, ec = t >> 6;
    float a = 0.f;
    for (int e = ec * 128; e < ec * 128 + 128; ++e) a += xsl[e] * wkh[e * 64 + p];
    ksp[ec][p] = a;
  }
  __syncthreads();
  if (t < 64) ks[t] = ksp[0][t] + ksp[1][t] + ksp[2][t] + ksp[3][t];
  __syncthreads();
  const float* wqh = wq + (size_t)h * E * P;
#pragma unroll
  for (int j = 0; j < 2; ++j) {
    int e = t + j * 256;
    float a = 0.f;
#pragma unroll 8
    for (int pp = 0; pp < P; ++pp) a += wqh[e * 64 + pp] * ks[pp];
    wqk[((size_t)b * H + h) * E + e] = a * 0.125f;
  }
}

// scores[b,h,s] = xb[b,s,:] . wqk[b,h,:]
__global__ __launch_bounds__(256) void k_scores(const unsigned short* __restrict__ xb,
                                                const float* __restrict__ wqk, float* __restrict__ scores) {
  int b = blockIdx.x, s0 = blockIdx.y * 64, t = threadIdx.x;
  __shared__ float xs[64][68];
  __shared__ float wt[8][68];
  float acc[2] = {0.f, 0.f};
  for (int ec = 0; ec < E; ec += 64) {
    {
      int row = t >> 2, cg = (t & 3) * 16;
      v8s v0 = *(const v8s*)(xb + ((size_t)b * S + s0 + row) * E + ec + cg);
      v8s v1 = *(const v8s*)(xb + ((size_t)b * S + s0 + row) * E + ec + cg + 8);
      float4 f0, f1, f2, f3;
      f0.x = bf2f((unsigned short)v0[0]); f0.y = bf2f((unsigned short)v0[1]);
      f0.z = bf2f((unsigned short)v0[2]); f0.w = bf2f((unsigned short)v0[3]);
      f1.x = bf2f((unsigned short)v0[4]); f1.y = bf2f((unsigned short)v0[5]);
      f1.z = bf2f((unsigned short)v0[6]); f1.w = bf2f((unsigned short)v0[7]);
      f2.x = bf2f((unsigned short)v1[0]); f2.y = bf2f((unsigned short)v1[1]);
      f2.z = bf2f((unsigned short)v1[2]); f2.w = bf2f((unsigned short)v1[3]);
      f3.x = bf2f((unsigned short)v1[4]); f3.y = bf2f((unsigned short)v1[5]);
      f3.z = bf2f((unsigned short)v1[6]); f3.w = bf2f((unsigned short)v1[7]);
      *(float4*)&xs[row][cg] = f0;
      *(float4*)&xs[row][cg + 4] = f1;
      *(float4*)&xs[row][cg + 8] = f2;
      *(float4*)&xs[row][cg + 12] = f3;
    }
    if (t < 128) {
      int hr = t >> 4, c4 = t & 15;
      float4 v = *(const float4*)(wqk + ((size_t)b * H + hr) * E + ec + c4 * 4);
      *(float4*)&wt[hr][c4 * 4] = v;
    }
    __syncthreads();
#pragma unroll
    for (int j = 0; j < 2; ++j) {
      int o = t + j * 256;
      int sl = o >> 3, hh = o & 7;
      float a = 0.f;
#pragma unroll
      for (int c4 = 0; c4 < 16; ++c4) {
        float4 xa = *(const float4*)&xs[sl][c4 * 4];
        float4 wa = *(const float4*)&wt[hh][c4 * 4];
        a += xa.x * wa.x + xa.y * wa.y + xa.z * wa.z + xa.w * wa.w;
      }
      acc[j] += a;
    }
    __syncthreads();
  }
#pragma unroll
  for (int j = 0; j < 2; ++j) {
    int o = t + j * 256;
    int sl = o >> 3, hh = o & 7;
    scores[((size_t)b * H + hh) * S + s0 + sl] = acc[j];
  }
}

__global__ __launch_bounds__(256) void k_softmax(const float* __restrict__ scores, float* __restrict__ attw,
                                                 float* __restrict__ att_out) {
  int bh = blockIdx.x, t = threadIdx.x;
  int b = bh >> 3, h = bh & 7;
  float v0 = scores[(size_t)bh * S + t];
  float v1 = scores[(size_t)bh * S + t + 256];
  float m = fmaxf(v0, v1);
#pragma unroll
  for (int off = 32; off; off >>= 1) m = fmaxf(m, __shfl_xor(m, off));
  __shared__ float rm[4], rs[4];
  if ((t & 63) == 0) rm[t >> 6] = m;
  __syncthreads();
  m = fmaxf(fmaxf(rm[0], rm[1]), fmaxf(rm[2], rm[3]));
  float e0 = __expf(v0 - m), e1 = __expf(v1 - m);
  float sm = e0 + e1;
#pragma unroll
  for (int off = 32; off; off >>= 1) sm += __shfl_xor(sm, off);
  if ((t & 63) == 0) rs[t >> 6] = sm;
  __syncthreads();
  float inv = 1.f / (rs[0] + rs[1] + rs[2] + rs[3]);
  float a0 = e0 * inv, a1 = e1 * inv;
  attw[(size_t)bh * S + t] = a0;
  attw[(size_t)bh * S + t + 256] = a1;
  att_out[((size_t)b * S + t) * H + h] = a0;
  att_out[((size_t)b * S + t + 256) * H + h] = a1;
}

// ---------------- r3-verbatim full-LDS GEMM core (best measured: 44.7us ffn1).
// global_load_lds w16, single LDS buf, 2 barriers/K-step, BK=32,
// granule swizzle g^=(row>>1)&3 (inverse-swz source + swz read).
template <int KD>
__device__ __forceinline__ void gemm_tile_gl(const unsigned short* __restrict__ A,
                                             const unsigned short* __restrict__ Bt,
                                             int lda, int ldb, int m0, int n0,
                                             unsigned short* As, unsigned short* Bs, v4f acc[4][4]) {
  const int t = threadIdx.x;
  const int l = t & 63, w = t >> 6;
  const int wr = w >> 1, wc = w & 1;
  const int lr = l >> 2, lg = l & 3;
  const int ch = l >> 4, r15 = l & 15;
  for (int kc = 0; kc < KD; kc += 32) {
#pragma unroll
    for (int cc = 0; cc < 2; ++cc) {
      int c = w * 2 + cc;
      int row = c * 16 + lr;
      int sg = lg ^ ((row >> 1) & 3);  // inverse-swizzled source granule
      const unsigned short* ga = A + (size_t)(m0 + row) * lda + kc + sg * 8;
      const unsigned short* gb = Bt + (size_t)(n0 + row) * ldb + kc + sg * 8;
      gl_lds16(ga, As + c * 512);
      gl_lds16(gb, Bs + c * 512);
    }
    __syncthreads();
    v8s af[4], bfr[4];
#pragma unroll
    for (int i = 0; i < 4; ++i) {
      int ra = wr * 64 + i * 16 + r15;
      af[i] = *(const v8s*)(As + ra * 32 + (ch ^ ((ra >> 1) & 3)) * 8);
      int rb = wc * 64 + i * 16 + r15;
      bfr[i] = *(const v8s*)(Bs + rb * 32 + (ch ^ ((rb >> 1) & 3)) * 8);
    }
#pragma unroll
    for (int i = 0; i < 4; ++i)
#pragma unroll
      for (int j = 0; j < 4; ++j)
        acc[i][j] = __builtin_amdgcn_mfma_f32_16x16x32_bf16(af[i], bfr[j], acc[i][j], 0, 0, 0);
    __syncthreads();
  }
}

// V-projection GEMM: vb = bf16((xb @ wv)*attw); sqnorm[h] += sum o^2
__global__ __launch_bounds__(256) void k_gemm_v(const unsigned short* __restrict__ xb,
                                                const unsigned short* __restrict__ wvt,
                                                const float* __restrict__ attw,
                                                unsigned short* __restrict__ vb,
                                                float* __restrict__ sqnorm) {
  __shared__ alignas(16) unsigned short As[4096], Bs[4096];
  int m0 = blockIdx.x * 128, n0 = blockIdx.y * 128;
  v4f acc[4][4] = {};
  gemm_tile_gl<512>(xb, wvt, 512, 512, m0, n0, As, Bs, acc);
  int t = threadIdx.x, l = t & 63, w = t >> 6, wr = w >> 1, wc = w & 1;
  int h = blockIdx.y * 2 + wc;
  float ssq = 0.f;
#pragma unroll
  for (int i = 0; i < 4; ++i) {
#pragma unroll
    for (int q = 0; q < 4; ++q) {
      int row = m0 + wr * 64 + i * 16 + (l >> 4) * 4 + q;
      int b = row >> 9, s = row & 511;
      float aw = attw[(size_t)(b * 8 + h) * 512 + s];
#pragma unroll
      for (int j = 0; j < 4; ++j) {
        int gc = n0 + wc * 64 + j * 16 + (l & 15);
        float o = acc[i][j][q] * aw;
        ssq += o * o;
        vb[(size_t)row * 512 + gc] = f2bf(o);
      }
    }
  }
#pragma unroll
  for (int off = 32; off; off >>= 1) ssq += __shfl_xor(ssq, off);
  if (l == 0) atomicAdd(&sqnorm[h], ssq);
}

// LN0 (wave per row, IN-PLACE over xb): xh := bf16(LN(perm(vb)*hs + xh))
__global__ __launch_bounds__(256) void k_ln0(const unsigned short* __restrict__ vb,
                                             unsigned short* xh,
                                             const float* __restrict__ sqnorm, const float* __restrict__ g,
                                             const float* __restrict__ bb) {
  __shared__ unsigned short perm[4][512];
  int t = threadIdx.x, w = t >> 6, l = t & 63;
  int r = blockIdx.x * 4 + w;
  *(v8s*)&perm[w][l * 8] = *(const v8s*)(vb + (size_t)r * 512 + l * 8);
  __syncthreads();
  v8s xv = *(const v8s*)(xh + (size_t)r * 512 + l * 8);
  float v[8];
#pragma unroll
  for (int j = 0; j < 8; ++j) {
    float hs = rsqrtf(fmaxf(sqnorm[j], 1e-12f));
    v[j] = bf2f(perm[w][j * 64 + l]) * hs + bf2f((unsigned short)xv[j]);
  }
  float sum = 0.f, sq = 0.f;
#pragma unroll
  for (int j = 0; j < 8; ++j) { sum += v[j]; sq += v[j] * v[j]; }
#pragma unroll
  for (int off = 32; off; off >>= 1) {
    sum += __shfl_xor(sum, off);
    sq += __shfl_xor(sq, off);
  }
  float mean = sum * (1.f / E);
  float var = fmaxf(sq * (1.f / E) - mean * mean, 0.f);
  float rstd = rsqrtf(var + 1e-3f);
  float4 g0 = *(const float4*)(g + l * 8), g1 = *(const float4*)(g + l * 8 + 4);
  float4 b0 = *(const float4*)(bb + l * 8), b1 = *(const float4*)(bb + l * 8 + 4);
  float gg[8] = {g0.x, g0.y, g0.z, g0.w, g1.x, g1.y, g1.z, g1.w};
  float bbv[8] = {b0.x, b0.y, b0.z, b0.w, b1.x, b1.y, b1.z, b1.w};
  v8s hv;
#pragma unroll
  for (int j = 0; j < 8; ++j) hv[j] = (short)f2bf((v[j] - mean) * rstd * gg[j] + bbv[j]);
  *(v8s*)(xh + (size_t)r * 512 + l * 8) = hv;
}

// FFN1: p1 = bf16(leaky_relu(hb @ w1 + b1)); rsump[row][by*2+wc] = partial sumsq
__global__ __launch_bounds__(256) void k_ffn1(const unsigned short* __restrict__ hb,
                                              const unsigned short* __restrict__ w1t,
                                              const float* __restrict__ b1, unsigned short* __restrict__ p1,
                                              float* __restrict__ rsump) {
  __shared__ alignas(16) unsigned short As[4096], Bs[4096];
  int m0 = blockIdx.x * 128, n0 = blockIdx.y * 128;
  v4f acc[4][4] = {};
  gemm_tile_gl<512>(hb, w1t, 512, 512, m0, n0, As, Bs, acc);
  int t = threadIdx.x, l = t & 63, w = t >> 6, wr = w >> 1, wc = w & 1;
  int colb = n0 + wc * 64 + (l & 15);
  float bias[4];
#pragma unroll
  for (int j = 0; j < 4; ++j) bias[j] = b1[colb + j * 16];
#pragma unroll
  for (int i = 0; i < 4; ++i) {
#pragma unroll
    for (int q = 0; q < 4; ++q) {
      int row = m0 + wr * 64 + i * 16 + (l >> 4) * 4 + q;
      float ps = 0.f;
#pragma unroll
      for (int j = 0; j < 4; ++j) {
        float v = acc[i][j][q] + bias[j];
        v = v > 0.f ? v : 0.2f * v;
        ps += v * v;
        p1[(size_t)row * FF + colb + j * 16] = f2bf(v);
      }
#pragma unroll
      for (int m = 1; m < 16; m <<= 1) ps += __shfl_xor(ps, m);
      if ((l & 15) == 0) rsump[(size_t)row * 24 + blockIdx.y * 2 + wc] = ps;
    }
  }
}

// FFN2: p2b = bf16((p1 @ w2)*rinv + b2 + hb); rinv computed in-block from rsump
__global__ __launch_bounds__(256) void k_ffn2(const unsigned short* __restrict__ p1,
                                              const unsigned short* __restrict__ w2t,
                                              const float* __restrict__ rsump, const float* __restrict__ b2,
                                              const unsigned short* __restrict__ hb,
                                              unsigned short* __restrict__ p2b) {
  __shared__ alignas(16) unsigned short As[4096], Bs[4096];
  __shared__ float rinv_l[128];
  int m0 = blockIdx.x * 128, n0 = blockIdx.y * 128;
  int t = threadIdx.x;
  if (t < 128) {
    float s = 0.f;
#pragma unroll
    for (int k = 0; k < 24; ++k) s += rsump[(size_t)(m0 + t) * 24 + k];
    rinv_l[t] = rsqrtf(fmaxf(s, 1e-12f));
  }
  v4f acc[4][4] = {};
  gemm_tile_gl<1536>(p1, w2t, 1536, 1536, m0, n0, As, Bs, acc);
  int l = t & 63, w = t >> 6, wr = w >> 1, wc = w & 1;
  int colb = n0 + wc * 64 + (l & 15);
  float bias[4];
#pragma unroll
  for (int j = 0; j < 4; ++j) bias[j] = b2[colb + j * 16];
#pragma unroll
  for (int i = 0; i < 4; ++i) {
#pragma unroll
    for (int q = 0; q < 4; ++q) {
      int row = m0 + wr * 64 + i * 16 + (l >> 4) * 4 + q;
      float rv = rinv_l[row - m0];
#pragma unroll
      for (int j = 0; j < 4; ++j) {
        size_t idx = (size_t)row * 512 + colb + j * 16;
        float o = acc[i][j][q] * rv + bias[j] + bf2f(hb[idx]);
        p2b[idx] = f2bf(o);
      }
    }
  }
}

// LN1 (wave per row): out = LN(p2b)
__global__ __launch_bounds__(256) void k_ln1(const unsigned short* __restrict__ p2b, const float* __restrict__ g,
                                             const float* __restrict__ bb, float* __restrict__ outp) {
  int t = threadIdx.x, w = t >> 6, l = t & 63;
  int r = blockIdx.x * 4 + w;
  v8s pv = *(const v8s*)(p2b + (size_t)r * 512 + l * 8);
  float v[8];
#pragma unroll
  for (int j = 0; j < 8; ++j) v[j] = bf2f((unsigned short)pv[j]);
  float sum = 0.f, sq = 0.f;
#pragma unroll
  for (int j = 0; j < 8; ++j) { sum += v[j]; sq += v[j] * v[j]; }
#pragma unroll
  for (int off = 32; off; off >>= 1) {
    sum += __shfl_xor(sum, off);
    sq += __shfl_xor(sq, off);
  }
  float mean = sum * (1.f / E);
  float var = fmaxf(sq * (1.f / E) - mean * mean, 0.f);
  float rstd = rsqrtf(var + 1e-3f);
  float4 g0 = *(const float4*)(g + l * 8), g1 = *(const float4*)(g + l * 8 + 4);
  float4 b0 = *(const float4*)(bb + l * 8), b1 = *(const float4*)(bb + l * 8 + 4);
  float gg[8] = {g0.x, g0.y, g0.z, g0.w, g1.x, g1.y, g1.z, g1.w};
  float bbv[8] = {b0.x, b0.y, b0.z, b0.w, b1.x, b1.y, b1.z, b1.w};
  float4 o0, o1;
  o0.x = (v[0] - mean) * rstd * gg[0] + bbv[0];
  o0.y = (v[1] - mean) * rstd * gg[1] + bbv[1];
  o0.z = (v[2] - mean) * rstd * gg[2] + bbv[2];
  o0.w = (v[3] - mean) * rstd * gg[3] + bbv[3];
  o1.x = (v[4] - mean) * rstd * gg[4] + bbv[4];
  o1.y = (v[5] - mean) * rstd * gg[5] + bbv[5];
  o1.z = (v[6] - mean) * rstd * gg[6] + bbv[6];
  o1.w = (v[7] - mean) * rstd * gg[7] + bbv[7];
  *(float4*)(outp + (size_t)r * 512 + l * 8) = o0;
  *(float4*)(outp + (size_t)r * 512 + l * 8 + 4) = o1;
}

}  // namespace

extern "C" void kernel_launch(void* const* d_in, const int* in_sizes, int n_in,
                              void* d_out, int out_size, void* d_ws, size_t ws_size,
                              hipStream_t stream) {
  const float* x = (const float*)d_in[0];
  const float* wq = (const float*)d_in[1];
  const float* wk = (const float*)d_in[2];
  const float* wv = (const float*)d_in[3];
  const float* ln0_g = (const float*)d_in[4];
  const float* ln0_b = (const float*)d_in[5];
  const float* w1 = (const float*)d_in[6];
  const float* b1 = (const float*)d_in[7];
  const float* w2 = (const float*)d_in[8];
  const float* b2 = (const float*)d_in[9];
  const float* ln1_g = (const float*)d_in[10];
  const float* ln1_b = (const float*)d_in[11];

  float* att_out = (float*)d_out;                  // [B,S,H]
  float* outp = (float*)d_out + (size_t)B * S * H; // [B,S,E]

  char* ws = (char*)d_ws;
  float* xsump = (float*)(ws + 0);                        // 1 MB  [B][16][E]
  float* wqkb = (float*)(ws + 1048576);                   // 512 KB
  float* scores = (float*)(ws + 1572864);                 // 512 KB
  float* attw = (float*)(ws + 2097152);                   // 512 KB
  float* sqnorm = (float*)(ws + 2621440);                 // 4 KB (pad)
  float* rsump = (float*)(ws + 2625536);                  // 1.5 MB [BS][24]
  unsigned short* w1t = (unsigned short*)(ws + 4263936);  // 1.5 MB [FF][E]
  unsigned short* w2t = (unsigned short*)(ws + 5836800);  // 1.5 MB [E][FF]
  unsigned short* wvt = (unsigned short*)(ws + 7409664);  // 512 KB [H*P][E]
  unsigned short* xb = (unsigned short*)(ws + 7933952);   // 16 MB [BS][E] bf16 (hb aliases after ln0)
  unsigned short* vb = (unsigned short*)(ws + 24711168);  // 16 MB [BS][512] bf16 (p2b aliases)
  unsigned short* p1 = (unsigned short*)(ws + 41488384);  // 48 MB [BS][FF] bf16
  unsigned short* hb = xb;                                // ln0 writes in place
  unsigned short* p2b = vb;                               // vb dead after ln0

  k_prep<<<704, 256, 0, stream>>>(w1, w2, wv, x, w1t, w2t, wvt, xb, xsump);
  k_wqk<<<dim3(B, H), 256, 0, stream>>>(xsump, wq, wk, wqkb, sqnorm);
  k_scores<<<dim3(B, S / 64), 256, 0, stream>>>(xb, wqkb, scores);
  k_softmax<<<B * H, 256, 0, stream>>>(scores, attw, att_out);
  k_gemm_v<<<dim3(BS / 128, 4), 256, 0, stream>>>(xb, wvt, attw, vb, sqnorm);
  k_ln0<<<BS / 4, 256, 0, stream>>>(vb, xb, sqnorm, ln0_g, ln0_b);
  k_ffn1<<<dim3(BS / 128, FF / 128), 256, 0, stream>>>(hb, w1t, b1, p1, rsump);
  k_ffn2<<<dim3(BS / 128, E / 128), 256, 0, stream>>>(p1, w2t, rsump, b2, hb, p2b);
  k_ln1<<<BS / 4, 256, 0, stream>>>(p2b, ln1_g, ln1_b, outp);
}

// Round 11
// 172.127 us; speedup vs baseline: 1.7763x; 1.0246x over previous
//
#include <hip/hip_runtime.h>
#include <hip/hip_bf16.h>

namespace {

constexpr int B = 32, S = 512, E = 512, H = 8, P = 64, FF = 1536;
constexpr int BS = B * S;

typedef short v8s __attribute__((ext_vector_type(8)));
typedef float v4f __attribute__((ext_vector_type(4)));

__device__ __forceinline__ float bf2f(unsigned short u) {
  return __uint_as_float(((unsigned int)u) << 16);
}
__device__ __forceinline__ unsigned short f2bf(float f) {
  __hip_bfloat16 h = __float2bfloat16(f);
  return *reinterpret_cast<unsigned short*>(&h);
}

__device__ __forceinline__ void gl_lds16(const unsigned short* g, unsigned short* l) {
  __builtin_amdgcn_global_load_lds((const __attribute__((address_space(1))) unsigned int*)g,
                                   (__attribute__((address_space(3))) unsigned int*)l, 16, 0, 0);
}

// ---------------- prep: weight transposes (blocks 0..447) + x->bf16/colsum (448..703) ----
__global__ __launch_bounds__(256) void k_prep(const float* __restrict__ w1, const float* __restrict__ w2,
                                              const float* __restrict__ wv, const float* __restrict__ x,
                                              unsigned short* __restrict__ w1t, unsigned short* __restrict__ w2t,
                                              unsigned short* __restrict__ wvt, unsigned short* __restrict__ xb,
                                              float* __restrict__ xsump) {
  __shared__ float tile[64][65];
  int id = blockIdx.x;
  int t = threadIdx.x;
  if (id >= 448) {
    int i = id - 448;
    int b = i >> 3, ch = i & 7;
    int c4 = (t & 127) * 4;
    int rh = t >> 7;
    const float* xp = x + ((size_t)b * S + ch * 64 + rh * 32) * E;
    unsigned short* xbp = xb + ((size_t)b * S + ch * 64 + rh * 32) * E;
    float ax = 0.f, ay = 0.f, az = 0.f, aw = 0.f;
    for (int s = 0; s < 32; ++s) {
      float4 v = *(const float4*)(xp + (size_t)s * E + c4);
      ax += v.x; ay += v.y; az += v.z; aw += v.w;
      ushort4 u;
      u.x = f2bf(v.x); u.y = f2bf(v.y); u.z = f2bf(v.z); u.w = f2bf(v.w);
      *(ushort4*)(xbp + (size_t)s * E + c4) = u;
    }
    float* xs = xsump + ((size_t)b * 16 + ch * 2 + rh) * E + c4;
    xs[0] = ax; xs[1] = ay; xs[2] = az; xs[3] = aw;
    return;
  }
  const float* inp;
  unsigned short* outp;
  int R, C, bx, by;
  size_t zo = 0;
  if (id < 192) {
    inp = w1; outp = w1t; R = 512; C = 1536; bx = id % 24; by = id / 24;
  } else if (id < 384) {
    int i = id - 192;
    inp = w2; outp = w2t; R = 1536; C = 512; bx = i & 7; by = i >> 3;
  } else {
    int i = id - 384;
    inp = wv; outp = wvt; R = 512; C = 64; bx = 0; by = i & 7; zo = (size_t)(i >> 3) * (512 * 64);
  }
  int c0 = bx * 64, r0 = by * 64;
#pragma unroll
  for (int j = 0; j < 4; ++j) {
    int i = t + j * 256;
    int rr = i >> 4, c4 = i & 15;
    float4 v = *(const float4*)(inp + zo + (size_t)(r0 + rr) * C + c0 + c4 * 4);
    tile[rr][c4 * 4 + 0] = v.x;
    tile[rr][c4 * 4 + 1] = v.y;
    tile[rr][c4 * 4 + 2] = v.z;
    tile[rr][c4 * 4 + 3] = v.w;
  }
  __syncthreads();
#pragma unroll
  for (int j = 0; j < 4; ++j) {
    int u = t + j * 256;
    int cr = u >> 4, q = u & 15;
    ushort4 o;
    o.x = f2bf(tile[q * 4 + 0][cr]);
    o.y = f2bf(tile[q * 4 + 1][cr]);
    o.z = f2bf(tile[q * 4 + 2][cr]);
    o.w = f2bf(tile[q * 4 + 3][cr]);
    *(ushort4*)(outp + zo + (size_t)(c0 + cr) * R + r0 + q * 4) = o;
  }
}

// ksum[p]=sum_e xsum[b,e]*wk[h,e,p]; wqk[b,h,e]=0.125*sum_p wq[h,e,p]*ksum[p]; zero sqnorm
__global__ __launch_bounds__(256) void k_wqk(const float* __restrict__ xsump, const float* __restrict__ wq,
                                             const float* __restrict__ wk, float* __restrict__ wqk,
                                             float* __restrict__ sqnorm) {
  int b = blockIdx.x, h = blockIdx.y, t = threadIdx.x;
  if (b == 0 && h == 0 && t < 8) sqnorm[t] = 0.f;
  __shared__ float xsl[E];
  __shared__ float ksp[4][64];
  __shared__ float ks[64];
#pragma unroll
  for (int j = 0; j < 2; ++j) {
    int e = t + j * 256;
    float s = 0.f;
#pragma unroll
    for (int c = 0; c < 16; ++c) s += xsump[((size_t)b * 16 + c) * E + e];
    xsl[e] = s;
  }
  __syncthreads();
  {
    const float* wkh = wk + (size_t)h * E * P;
    int p = t & 63, ec = t >> 6;
    float a = 0.f;
    for (int e = ec * 128; e < ec * 128 + 128; ++e) a += xsl[e] * wkh[e * 64 + p];
    ksp[ec][p] = a;
  }
  __syncthreads();
  if (t < 64) ks[t] = ksp[0][t] + ksp[1][t] + ksp[2][t] + ksp[3][t];
  __syncthreads();
  const float* wqh = wq + (size_t)h * E * P;
#pragma unroll
  for (int j = 0; j < 2; ++j) {
    int e = t + j * 256;
    float a = 0.f;
#pragma unroll 8
    for (int pp = 0; pp < P; ++pp) a += wqh[e * 64 + pp] * ks[pp];
    wqk[((size_t)b * H + h) * E + e] = a * 0.125f;
  }
}

// scores[b,h,s] = xb[b,s,:] . wqk[b,h,:]
__global__ __launch_bounds__(256) void k_scores(const unsigned short* __restrict__ xb,
                                                const float* __restrict__ wqk, float* __restrict__ scores) {
  int b = blockIdx.x, s0 = blockIdx.y * 64, t = threadIdx.x;
  __shared__ float xs[64][68];
  __shared__ float wt[8][68];
  float acc[2] = {0.f, 0.f};
  for (int ec = 0; ec < E; ec += 64) {
    {
      int row = t >> 2, cg = (t & 3) * 16;
      v8s v0 = *(const v8s*)(xb + ((size_t)b * S + s0 + row) * E + ec + cg);
      v8s v1 = *(const v8s*)(xb + ((size_t)b * S + s0 + row) * E + ec + cg + 8);
      float4 f0, f1, f2, f3;
      f0.x = bf2f((unsigned short)v0[0]); f0.y = bf2f((unsigned short)v0[1]);
      f0.z = bf2f((unsigned short)v0[2]); f0.w = bf2f((unsigned short)v0[3]);
      f1.x = bf2f((unsigned short)v0[4]); f1.y = bf2f((unsigned short)v0[5]);
      f1.z = bf2f((unsigned short)v0[6]); f1.w = bf2f((unsigned short)v0[7]);
      f2.x = bf2f((unsigned short)v1[0]); f2.y = bf2f((unsigned short)v1[1]);
      f2.z = bf2f((unsigned short)v1[2]); f2.w = bf2f((unsigned short)v1[3]);
      f3.x = bf2f((unsigned short)v1[4]); f3.y = bf2f((unsigned short)v1[5]);
      f3.z = bf2f((unsigned short)v1[6]); f3.w = bf2f((unsigned short)v1[7]);
      *(float4*)&xs[row][cg] = f0;
      *(float4*)&xs[row][cg + 4] = f1;
      *(float4*)&xs[row][cg + 8] = f2;
      *(float4*)&xs[row][cg + 12] = f3;
    }
    if (t < 128) {
      int hr = t >> 4, c4 = t & 15;
      float4 v = *(const float4*)(wqk + ((size_t)b * H + hr) * E + ec + c4 * 4);
      *(float4*)&wt[hr][c4 * 4] = v;
    }
    __syncthreads();
#pragma unroll
    for (int j = 0; j < 2; ++j) {
      int o = t + j * 256;
      int sl = o >> 3, hh = o & 7;
      float a = 0.f;
#pragma unroll
      for (int c4 = 0; c4 < 16; ++c4) {
        float4 xa = *(const float4*)&xs[sl][c4 * 4];
        float4 wa = *(const float4*)&wt[hh][c4 * 4];
        a += xa.x * wa.x + xa.y * wa.y + xa.z * wa.z + xa.w * wa.w;
      }
      acc[j] += a;
    }
    __syncthreads();
  }
#pragma unroll
  for (int j = 0; j < 2; ++j) {
    int o = t + j * 256;
    int sl = o >> 3, hh = o & 7;
    scores[((size_t)b * H + hh) * S + s0 + sl] = acc[j];
  }
}

__global__ __launch_bounds__(256) void k_softmax(const float* __restrict__ scores, float* __restrict__ attw,
                                                 float* __restrict__ att_out) {
  int bh = blockIdx.x, t = threadIdx.x;
  int b = bh >> 3, h = bh & 7;
  float v0 = scores[(size_t)bh * S + t];
  float v1 = scores[(size_t)bh * S + t + 256];
  float m = fmaxf(v0, v1);
#pragma unroll
  for (int off = 32; off; off >>= 1) m = fmaxf(m, __shfl_xor(m, off));
  __shared__ float rm[4], rs[4];
  if ((t & 63) == 0) rm[t >> 6] = m;
  __syncthreads();
  m = fmaxf(fmaxf(rm[0], rm[1]), fmaxf(rm[2], rm[3]));
  float e0 = __expf(v0 - m), e1 = __expf(v1 - m);
  float sm = e0 + e1;
#pragma unroll
  for (int off = 32; off; off >>= 1) sm += __shfl_xor(sm, off);
  if ((t & 63) == 0) rs[t >> 6] = sm;
  __syncthreads();
  float inv = 1.f / (rs[0] + rs[1] + rs[2] + rs[3]);
  float a0 = e0 * inv, a1 = e1 * inv;
  attw[(size_t)bh * S + t] = a0;
  attw[(size_t)bh * S + t + 256] = a1;
  att_out[((size_t)b * S + t) * H + h] = a0;
  att_out[((size_t)b * S + t + 256) * H + h] = a1;
}

// ---------------- r3-verbatim full-LDS GEMM core, BK=32 (control; best measured) ----
template <int KD>
__device__ __forceinline__ void gemm_tile_gl(const unsigned short* __restrict__ A,
                                             const unsigned short* __restrict__ Bt,
                                             int lda, int ldb, int m0, int n0,
                                             unsigned short* As, unsigned short* Bs, v4f acc[4][4]) {
  const int t = threadIdx.x;
  const int l = t & 63, w = t >> 6;
  const int wr = w >> 1, wc = w & 1;
  const int lr = l >> 2, lg = l & 3;
  const int ch = l >> 4, r15 = l & 15;
  for (int kc = 0; kc < KD; kc += 32) {
#pragma unroll
    for (int cc = 0; cc < 2; ++cc) {
      int c = w * 2 + cc;
      int row = c * 16 + lr;
      int sg = lg ^ ((row >> 1) & 3);  // inverse-swizzled source granule
      const unsigned short* ga = A + (size_t)(m0 + row) * lda + kc + sg * 8;
      const unsigned short* gb = Bt + (size_t)(n0 + row) * ldb + kc + sg * 8;
      gl_lds16(ga, As + c * 512);
      gl_lds16(gb, Bs + c * 512);
    }
    __syncthreads();
    v8s af[4], bfr[4];
#pragma unroll
    for (int i = 0; i < 4; ++i) {
      int ra = wr * 64 + i * 16 + r15;
      af[i] = *(const v8s*)(As + ra * 32 + (ch ^ ((ra >> 1) & 3)) * 8);
      int rb = wc * 64 + i * 16 + r15;
      bfr[i] = *(const v8s*)(Bs + rb * 32 + (ch ^ ((rb >> 1) & 3)) * 8);
    }
#pragma unroll
    for (int i = 0; i < 4; ++i)
#pragma unroll
      for (int j = 0; j < 4; ++j)
        acc[i][j] = __builtin_amdgcn_mfma_f32_16x16x32_bf16(af[i], bfr[j], acc[i][j], 0, 0, 0);
    __syncthreads();
  }
}

// ---------------- BK=64 single-buffer variant: same 2-barrier semantics, half the
// drain+barrier events per K. Chunk = 8 rows x 64 k (1KB); swizzle g^=(row&7).
template <int KD>
__device__ __forceinline__ void gemm_tile_gl64(const unsigned short* __restrict__ A,
                                               const unsigned short* __restrict__ Bt,
                                               int lda, int ldb, int m0, int n0,
                                               unsigned short* As, unsigned short* Bs, v4f acc[4][4]) {
  const int t = threadIdx.x;
  const int l = t & 63, w = t >> 6;
  const int wr = w >> 1, wc = w & 1;
  const int ch = l >> 4, r15 = l & 15;
  const int lr = l >> 3, lg = l & 7;  // staging: row-in-chunk, lane granule
  for (int kc = 0; kc < KD; kc += 64) {
#pragma unroll
    for (int cc = 0; cc < 4; ++cc) {
      int c = w * 4 + cc;  // chunk of 8 rows x 64k = 1 KB; A and B each 16 chunks
      int row = c * 8 + lr;
      int sg = lg ^ (row & 7);  // inverse-swizzled source granule
      gl_lds16(A + (size_t)(m0 + row) * lda + kc + sg * 8, As + c * 512);
      gl_lds16(Bt + (size_t)(n0 + row) * ldb + kc + sg * 8, Bs + c * 512);
    }
    __syncthreads();  // drains vmcnt(0): tile visible
#pragma unroll
    for (int kk = 0; kk < 2; ++kk) {
      v8s af[4], bfr[4];
#pragma unroll
      for (int i = 0; i < 4; ++i) {
        int ra = wr * 64 + i * 16 + r15;
        af[i] = *(const v8s*)(As + ra * 64 + (((kk * 4 + ch) ^ (ra & 7)) * 8));
        int rb = wc * 64 + i * 16 + r15;
        bfr[i] = *(const v8s*)(Bs + rb * 64 + (((kk * 4 + ch) ^ (rb & 7)) * 8));
      }
      __builtin_amdgcn_s_setprio(1);
#pragma unroll
      for (int i = 0; i < 4; ++i)
#pragma unroll
        for (int j = 0; j < 4; ++j)
          acc[i][j] = __builtin_amdgcn_mfma_f32_16x16x32_bf16(af[i], bfr[j], acc[i][j], 0, 0, 0);
      __builtin_amdgcn_s_setprio(0);
    }
    __syncthreads();  // all reads done before next stage overwrites
  }
}

// V-projection GEMM (BK=64): vb = bf16((xb @ wv)*attw); sqnorm[h] += sum o^2
__global__ __launch_bounds__(256) void k_gemm_v(const unsigned short* __restrict__ xb,
                                                const unsigned short* __restrict__ wvt,
                                                const float* __restrict__ attw,
                                                unsigned short* __restrict__ vb,
                                                float* __restrict__ sqnorm) {
  __shared__ alignas(16) unsigned short As[8192], Bs[8192];
  int m0 = blockIdx.x * 128, n0 = blockIdx.y * 128;
  v4f acc[4][4] = {};
  gemm_tile_gl64<512>(xb, wvt, 512, 512, m0, n0, As, Bs, acc);
  int t = threadIdx.x, l = t & 63, w = t >> 6, wr = w >> 1, wc = w & 1;
  int h = blockIdx.y * 2 + wc;
  float ssq = 0.f;
#pragma unroll
  for (int i = 0; i < 4; ++i) {
#pragma unroll
    for (int q = 0; q < 4; ++q) {
      int row = m0 + wr * 64 + i * 16 + (l >> 4) * 4 + q;
      int b = row >> 9, s = row & 511;
      float aw = attw[(size_t)(b * 8 + h) * 512 + s];
#pragma unroll
      for (int j = 0; j < 4; ++j) {
        int gc = n0 + wc * 64 + j * 16 + (l & 15);
        float o = acc[i][j][q] * aw;
        ssq += o * o;
        vb[(size_t)row * 512 + gc] = f2bf(o);
      }
    }
  }
#pragma unroll
  for (int off = 32; off; off >>= 1) ssq += __shfl_xor(ssq, off);
  if (l == 0) atomicAdd(&sqnorm[h], ssq);
}

// LN0 (wave per row, IN-PLACE over xb): xh := bf16(LN(perm(vb)*hs + xh))
__global__ __launch_bounds__(256) void k_ln0(const unsigned short* __restrict__ vb,
                                             unsigned short* xh,
                                             const float* __restrict__ sqnorm, const float* __restrict__ g,
                                             const float* __restrict__ bb) {
  __shared__ unsigned short perm[4][512];
  int t = threadIdx.x, w = t >> 6, l = t & 63;
  int r = blockIdx.x * 4 + w;
  *(v8s*)&perm[w][l * 8] = *(const v8s*)(vb + (size_t)r * 512 + l * 8);
  __syncthreads();
  v8s xv = *(const v8s*)(xh + (size_t)r * 512 + l * 8);
  float v[8];
#pragma unroll
  for (int j = 0; j < 8; ++j) {
    float hs = rsqrtf(fmaxf(sqnorm[j], 1e-12f));
    v[j] = bf2f(perm[w][j * 64 + l]) * hs + bf2f((unsigned short)xv[j]);
  }
  float sum = 0.f, sq = 0.f;
#pragma unroll
  for (int j = 0; j < 8; ++j) { sum += v[j]; sq += v[j] * v[j]; }
#pragma unroll
  for (int off = 32; off; off >>= 1) {
    sum += __shfl_xor(sum, off);
    sq += __shfl_xor(sq, off);
  }
  float mean = sum * (1.f / E);
  float var = fmaxf(sq * (1.f / E) - mean * mean, 0.f);
  float rstd = rsqrtf(var + 1e-3f);
  float4 g0 = *(const float4*)(g + l * 8), g1 = *(const float4*)(g + l * 8 + 4);
  float4 b0 = *(const float4*)(bb + l * 8), b1 = *(const float4*)(bb + l * 8 + 4);
  float gg[8] = {g0.x, g0.y, g0.z, g0.w, g1.x, g1.y, g1.z, g1.w};
  float bbv[8] = {b0.x, b0.y, b0.z, b0.w, b1.x, b1.y, b1.z, b1.w};
  v8s hv;
#pragma unroll
  for (int j = 0; j < 8; ++j) hv[j] = (short)f2bf((v[j] - mean) * rstd * gg[j] + bbv[j]);
  *(v8s*)(xh + (size_t)r * 512 + l * 8) = hv;
}

// FFN1 (BK=64): p1 = bf16(leaky_relu(hb @ w1 + b1)); rsump partial sumsq
__global__ __launch_bounds__(256) void k_ffn1(const unsigned short* __restrict__ hb,
                                              const unsigned short* __restrict__ w1t,
                                              const float* __restrict__ b1, unsigned short* __restrict__ p1,
                                              float* __restrict__ rsump) {
  __shared__ alignas(16) unsigned short As[8192], Bs[8192];
  int m0 = blockIdx.x * 128, n0 = blockIdx.y * 128;
  v4f acc[4][4] = {};
  gemm_tile_gl64<512>(hb, w1t, 512, 512, m0, n0, As, Bs, acc);
  int t = threadIdx.x, l = t & 63, w = t >> 6, wr = w >> 1, wc = w & 1;
  int colb = n0 + wc * 64 + (l & 15);
  float bias[4];
#pragma unroll
  for (int j = 0; j < 4; ++j) bias[j] = b1[colb + j * 16];
#pragma unroll
  for (int i = 0; i < 4; ++i) {
#pragma unroll
    for (int q = 0; q < 4; ++q) {
      int row = m0 + wr * 64 + i * 16 + (l >> 4) * 4 + q;
      float ps = 0.f;
#pragma unroll
      for (int j = 0; j < 4; ++j) {
        float v = acc[i][j][q] + bias[j];
        v = v > 0.f ? v : 0.2f * v;
        ps += v * v;
        p1[(size_t)row * FF + colb + j * 16] = f2bf(v);
      }
#pragma unroll
      for (int m = 1; m < 16; m <<= 1) ps += __shfl_xor(ps, m);
      if ((l & 15) == 0) rsump[(size_t)row * 24 + blockIdx.y * 2 + wc] = ps;
    }
  }
}

// FFN2 (BK=32 control, r3-verbatim): p2b = bf16((p1 @ w2)*rinv + b2 + hb)
__global__ __launch_bounds__(256) void k_ffn2(const unsigned short* __restrict__ p1,
                                              const unsigned short* __restrict__ w2t,
                                              const float* __restrict__ rsump, const float* __restrict__ b2,
                                              const unsigned short* __restrict__ hb,
                                              unsigned short* __restrict__ p2b) {
  __shared__ alignas(16) unsigned short As[4096], Bs[4096];
  __shared__ float rinv_l[128];
  int m0 = blockIdx.x * 128, n0 = blockIdx.y * 128;
  int t = threadIdx.x;
  if (t < 128) {
    float s = 0.f;
#pragma unroll
    for (int k = 0; k < 24; ++k) s += rsump[(size_t)(m0 + t) * 24 + k];
    rinv_l[t] = rsqrtf(fmaxf(s, 1e-12f));
  }
  v4f acc[4][4] = {};
  gemm_tile_gl<1536>(p1, w2t, 1536, 1536, m0, n0, As, Bs, acc);
  int l = t & 63, w = t >> 6, wr = w >> 1, wc = w & 1;
  int colb = n0 + wc * 64 + (l & 15);
  float bias[4];
#pragma unroll
  for (int j = 0; j < 4; ++j) bias[j] = b2[colb + j * 16];
#pragma unroll
  for (int i = 0; i < 4; ++i) {
#pragma unroll
    for (int q = 0; q < 4; ++q) {
      int row = m0 + wr * 64 + i * 16 + (l >> 4) * 4 + q;
      float rv = rinv_l[row - m0];
#pragma unroll
      for (int j = 0; j < 4; ++j) {
        size_t idx = (size_t)row * 512 + colb + j * 16;
        float o = acc[i][j][q] * rv + bias[j] + bf2f(hb[idx]);
        p2b[idx] = f2bf(o);
      }
    }
  }
}

// LN1 (wave per row): out = LN(p2b)
__global__ __launch_bounds__(256) void k_ln1(const unsigned short* __restrict__ p2b, const float* __restrict__ g,
                                             const float* __restrict__ bb, float* __restrict__ outp) {
  int t = threadIdx.x, w = t >> 6, l = t & 63;
  int r = blockIdx.x * 4 + w;
  v8s pv = *(const v8s*)(p2b + (size_t)r * 512 + l * 8);
  float v[8];
#pragma unroll
  for (int j = 0; j < 8; ++j) v[j] = bf2f((unsigned short)pv[j]);
  float sum = 0.f, sq = 0.f;
#pragma unroll
  for (int j = 0; j < 8; ++j) { sum += v[j]; sq += v[j] * v[j]; }
#pragma unroll
  for (int off = 32; off; off >>= 1) {
    sum += __shfl_xor(sum, off);
    sq += __shfl_xor(sq, off);
  }
  float mean = sum * (1.f / E);
  float var = fmaxf(sq * (1.f / E) - mean * mean, 0.f);
  float rstd = rsqrtf(var + 1e-3f);
  float4 g0 = *(const float4*)(g + l * 8), g1 = *(const float4*)(g + l * 8 + 4);
  float4 b0 = *(const float4*)(bb + l * 8), b1 = *(const float4*)(bb + l * 8 + 4);
  float gg[8] = {g0.x, g0.y, g0.z, g0.w, g1.x, g1.y, g1.z, g1.w};
  float bbv[8] = {b0.x, b0.y, b0.z, b0.w, b1.x, b1.y, b1.z, b1.w};
  float4 o0, o1;
  o0.x = (v[0] - mean) * rstd * gg[0] + bbv[0];
  o0.y = (v[1] - mean) * rstd * gg[1] + bbv[1];
  o0.z = (v[2] - mean) * rstd * gg[2] + bbv[2];
  o0.w = (v[3] - mean) * rstd * gg[3] + bbv[3];
  o1.x = (v[4] - mean) * rstd * gg[4] + bbv[4];
  o1.y = (v[5] - mean) * rstd * gg[5] + bbv[5];
  o1.z = (v[6] - mean) * rstd * gg[6] + bbv[6];
  o1.w = (v[7] - mean) * rstd * gg[7] + bbv[7];
  *(float4*)(outp + (size_t)r * 512 + l * 8) = o0;
  *(float4*)(outp + (size_t)r * 512 + l * 8 + 4) = o1;
}

}  // namespace

extern "C" void kernel_launch(void* const* d_in, const int* in_sizes, int n_in,
                              void* d_out, int out_size, void* d_ws, size_t ws_size,
                              hipStream_t stream) {
  const float* x = (const float*)d_in[0];
  const float* wq = (const float*)d_in[1];
  const float* wk = (const float*)d_in[2];
  const float* wv = (const float*)d_in[3];
  const float* ln0_g = (const float*)d_in[4];
  const float* ln0_b = (const float*)d_in[5];
  const float* w1 = (const float*)d_in[6];
  const float* b1 = (const float*)d_in[7];
  const float* w2 = (const float*)d_in[8];
  const float* b2 = (const float*)d_in[9];
  const float* ln1_g = (const float*)d_in[10];
  const float* ln1_b = (const float*)d_in[11];

  float* att_out = (float*)d_out;                  // [B,S,H]
  float* outp = (float*)d_out + (size_t)B * S * H; // [B,S,E]

  char* ws = (char*)d_ws;
  float* xsump = (float*)(ws + 0);                        // 1 MB  [B][16][E]
  float* wqkb = (float*)(ws + 1048576);                   // 512 KB
  float* scores = (float*)(ws + 1572864);                 // 512 KB
  float* attw = (float*)(ws + 2097152);                   // 512 KB
  float* sqnorm = (float*)(ws + 2621440);                 // 4 KB (pad)
  float* rsump = (float*)(ws + 2625536);                  // 1.5 MB [BS][24]
  unsigned short* w1t = (unsigned short*)(ws + 4263936);  // 1.5 MB [FF][E]
  unsigned short* w2t = (unsigned short*)(ws + 5836800);  // 1.5 MB [E][FF]
  unsigned short* wvt = (unsigned short*)(ws + 7409664);  // 512 KB [H*P][E]
  unsigned short* xb = (unsigned short*)(ws + 7933952);   // 16 MB [BS][E] bf16 (hb aliases after ln0)
  unsigned short* vb = (unsigned short*)(ws + 24711168);  // 16 MB [BS][512] bf16 (p2b aliases)
  unsigned short* p1 = (unsigned short*)(ws + 41488384);  // 48 MB [BS][FF] bf16
  unsigned short* hb = xb;                                // ln0 writes in place
  unsigned short* p2b = vb;                               // vb dead after ln0

  k_prep<<<704, 256, 0, stream>>>(w1, w2, wv, x, w1t, w2t, wvt, xb, xsump);
  k_wqk<<<dim3(B, H), 256, 0, stream>>>(xsump, wq, wk, wqkb, sqnorm);
  k_scores<<<dim3(B, S / 64), 256, 0, stream>>>(xb, wqkb, scores);
  k_softmax<<<B * H, 256, 0, stream>>>(scores, attw, att_out);
  k_gemm_v<<<dim3(BS / 128, 4), 256, 0, stream>>>(xb, wvt, attw, vb, sqnorm);
  k_ln0<<<BS / 4, 256, 0, stream>>>(vb, xb, sqnorm, ln0_g, ln0_b);
  k_ffn1<<<dim3(BS / 128, FF / 128), 256, 0, stream>>>(hb, w1t, b1, p1, rsump);
  k_ffn2<<<dim3(BS / 128, E / 128), 256, 0, stream>>>(p1, w2t, rsump, b2, hb, p2b);
  k_ln1<<<BS / 4, 256, 0, stream>>>(p2b, ln1_g, ln1_b, outp);
}

// Round 12
// 147.278 us; speedup vs baseline: 2.0760x; 1.1687x over previous
//
#include <hip/hip_runtime.h>
#include <hip/hip_bf16.h>

namespace {

constexpr int B = 32, S = 512, E = 512, H = 8, P = 64, FF = 1536;
constexpr int BS = B * S;

typedef short v8s __attribute__((ext_vector_type(8)));
typedef float v4f __attribute__((ext_vector_type(4)));

__device__ __forceinline__ float bf2f(unsigned short u) {
  return __uint_as_float(((unsigned int)u) << 16);
}
__device__ __forceinline__ unsigned short f2bf(float f) {
  __hip_bfloat16 h = __float2bfloat16(f);
  return *reinterpret_cast<unsigned short*>(&h);
}

__device__ __forceinline__ void gl_lds16(const unsigned short* g, unsigned short* l) {
  __builtin_amdgcn_global_load_lds((const __attribute__((address_space(1))) unsigned int*)g,
                                   (__attribute__((address_space(3))) unsigned int*)l, 16, 0, 0);
}

// ---------------- prep: weight transposes (blocks 0..447) + x->bf16/colsum (448..703) ----
__global__ __launch_bounds__(256) void k_prep(const float* __restrict__ w1, const float* __restrict__ w2,
                                              const float* __restrict__ wv, const float* __restrict__ x,
                                              unsigned short* __restrict__ w1t, unsigned short* __restrict__ w2t,
                                              unsigned short* __restrict__ wvt, unsigned short* __restrict__ xb,
                                              float* __restrict__ xsump) {
  __shared__ float tile[64][65];
  int id = blockIdx.x;
  int t = threadIdx.x;
  if (id >= 448) {
    int i = id - 448;
    int b = i >> 3, ch = i & 7;
    int c4 = (t & 127) * 4;
    int rh = t >> 7;
    const float* xp = x + ((size_t)b * S + ch * 64 + rh * 32) * E;
    unsigned short* xbp = xb + ((size_t)b * S + ch * 64 + rh * 32) * E;
    float ax = 0.f, ay = 0.f, az = 0.f, aw = 0.f;
    for (int s = 0; s < 32; ++s) {
      float4 v = *(const float4*)(xp + (size_t)s * E + c4);
      ax += v.x; ay += v.y; az += v.z; aw += v.w;
      ushort4 u;
      u.x = f2bf(v.x); u.y = f2bf(v.y); u.z = f2bf(v.z); u.w = f2bf(v.w);
      *(ushort4*)(xbp + (size_t)s * E + c4) = u;
    }
    float* xs = xsump + ((size_t)b * 16 + ch * 2 + rh) * E + c4;
    xs[0] = ax; xs[1] = ay; xs[2] = az; xs[3] = aw;
    return;
  }
  const float* inp;
  unsigned short* outp;
  int R, C, bx, by;
  size_t zo = 0;
  if (id < 192) {
    inp = w1; outp = w1t; R = 512; C = 1536; bx = id % 24; by = id / 24;
  } else if (id < 384) {
    int i = id - 192;
    inp = w2; outp = w2t; R = 1536; C = 512; bx = i & 7; by = i >> 3;
  } else {
    int i = id - 384;
    inp = wv; outp = wvt; R = 512; C = 64; bx = 0; by = i & 7; zo = (size_t)(i >> 3) * (512 * 64);
  }
  int c0 = bx * 64, r0 = by * 64;
#pragma unroll
  for (int j = 0; j < 4; ++j) {
    int i = t + j * 256;
    int rr = i >> 4, c4 = i & 15;
    float4 v = *(const float4*)(inp + zo + (size_t)(r0 + rr) * C + c0 + c4 * 4);
    tile[rr][c4 * 4 + 0] = v.x;
    tile[rr][c4 * 4 + 1] = v.y;
    tile[rr][c4 * 4 + 2] = v.z;
    tile[rr][c4 * 4 + 3] = v.w;
  }
  __syncthreads();
#pragma unroll
  for (int j = 0; j < 4; ++j) {
    int u = t + j * 256;
    int cr = u >> 4, q = u & 15;
    ushort4 o;
    o.x = f2bf(tile[q * 4 + 0][cr]);
    o.y = f2bf(tile[q * 4 + 1][cr]);
    o.z = f2bf(tile[q * 4 + 2][cr]);
    o.w = f2bf(tile[q * 4 + 3][cr]);
    *(ushort4*)(outp + zo + (size_t)(c0 + cr) * R + r0 + q * 4) = o;
  }
}

// ksum/wqk; zeroes the 64 padded sqnorm_p slots
__global__ __launch_bounds__(256) void k_wqk(const float* __restrict__ xsump, const float* __restrict__ wq,
                                             const float* __restrict__ wk, float* __restrict__ wqk,
                                             float* __restrict__ sqnorm_p) {
  int b = blockIdx.x, h = blockIdx.y, t = threadIdx.x;
  if (b == 0 && h == 0 && t < 64) sqnorm_p[t * 16] = 0.f;
  __shared__ float xsl[E];
  __shared__ float ksp[4][64];
  __shared__ float ks[64];
#pragma unroll
  for (int j = 0; j < 2; ++j) {
    int e = t + j * 256;
    float s = 0.f;
#pragma unroll
    for (int c = 0; c < 16; ++c) s += xsump[((size_t)b * 16 + c) * E + e];
    xsl[e] = s;
  }
  __syncthreads();
  {
    const float* wkh = wk + (size_t)h * E * P;
    int p = t & 63, ec = t >> 6;
    float a = 0.f;
    for (int e = ec * 128; e < ec * 128 + 128; ++e) a += xsl[e] * wkh[e * 64 + p];
    ksp[ec][p] = a;
  }
  __syncthreads();
  if (t < 64) ks[t] = ksp[0][t] + ksp[1][t] + ksp[2][t] + ksp[3][t];
  __syncthreads();
  const float* wqh = wq + (size_t)h * E * P;
#pragma unroll
  for (int j = 0; j < 2; ++j) {
    int e = t + j * 256;
    float a = 0.f;
#pragma unroll 8
    for (int pp = 0; pp < P; ++pp) a += wqh[e * 64 + pp] * ks[pp];
    wqk[((size_t)b * H + h) * E + e] = a * 0.125f;
  }
}

// scores[b,h,s] = xb[b,s,:] . wqk[b,h,:]
__global__ __launch_bounds__(256) void k_scores(const unsigned short* __restrict__ xb,
                                                const float* __restrict__ wqk, float* __restrict__ scores) {
  int b = blockIdx.x, s0 = blockIdx.y * 64, t = threadIdx.x;
  __shared__ float xs[64][68];
  __shared__ float wt[8][68];
  float acc[2] = {0.f, 0.f};
  for (int ec = 0; ec < E; ec += 64) {
    {
      int row = t >> 2, cg = (t & 3) * 16;
      v8s v0 = *(const v8s*)(xb + ((size_t)b * S + s0 + row) * E + ec + cg);
      v8s v1 = *(const v8s*)(xb + ((size_t)b * S + s0 + row) * E + ec + cg + 8);
      float4 f0, f1, f2, f3;
      f0.x = bf2f((unsigned short)v0[0]); f0.y = bf2f((unsigned short)v0[1]);
      f0.z = bf2f((unsigned short)v0[2]); f0.w = bf2f((unsigned short)v0[3]);
      f1.x = bf2f((unsigned short)v0[4]); f1.y = bf2f((unsigned short)v0[5]);
      f1.z = bf2f((unsigned short)v0[6]); f1.w = bf2f((unsigned short)v0[7]);
      f2.x = bf2f((unsigned short)v1[0]); f2.y = bf2f((unsigned short)v1[1]);
      f2.z = bf2f((unsigned short)v1[2]); f2.w = bf2f((unsigned short)v1[3]);
      f3.x = bf2f((unsigned short)v1[4]); f3.y = bf2f((unsigned short)v1[5]);
      f3.z = bf2f((unsigned short)v1[6]); f3.w = bf2f((unsigned short)v1[7]);
      *(float4*)&xs[row][cg] = f0;
      *(float4*)&xs[row][cg + 4] = f1;
      *(float4*)&xs[row][cg + 8] = f2;
      *(float4*)&xs[row][cg + 12] = f3;
    }
    if (t < 128) {
      int hr = t >> 4, c4 = t & 15;
      float4 v = *(const float4*)(wqk + ((size_t)b * H + hr) * E + ec + c4 * 4);
      *(float4*)&wt[hr][c4 * 4] = v;
    }
    __syncthreads();
#pragma unroll
    for (int j = 0; j < 2; ++j) {
      int o = t + j * 256;
      int sl = o >> 3, hh = o & 7;
      float a = 0.f;
#pragma unroll
      for (int c4 = 0; c4 < 16; ++c4) {
        float4 xa = *(const float4*)&xs[sl][c4 * 4];
        float4 wa = *(const float4*)&wt[hh][c4 * 4];
        a += xa.x * wa.x + xa.y * wa.y + xa.z * wa.z + xa.w * wa.w;
      }
      acc[j] += a;
    }
    __syncthreads();
  }
#pragma unroll
  for (int j = 0; j < 2; ++j) {
    int o = t + j * 256;
    int sl = o >> 3, hh = o & 7;
    scores[((size_t)b * H + hh) * S + s0 + sl] = acc[j];
  }
}

__global__ __launch_bounds__(256) void k_softmax(const float* __restrict__ scores, float* __restrict__ attw,
                                                 float* __restrict__ att_out) {
  int bh = blockIdx.x, t = threadIdx.x;
  int b = bh >> 3, h = bh & 7;
  float v0 = scores[(size_t)bh * S + t];
  float v1 = scores[(size_t)bh * S + t + 256];
  float m = fmaxf(v0, v1);
#pragma unroll
  for (int off = 32; off; off >>= 1) m = fmaxf(m, __shfl_xor(m, off));
  __shared__ float rm[4], rs[4];
  if ((t & 63) == 0) rm[t >> 6] = m;
  __syncthreads();
  m = fmaxf(fmaxf(rm[0], rm[1]), fmaxf(rm[2], rm[3]));
  float e0 = __expf(v0 - m), e1 = __expf(v1 - m);
  float sm = e0 + e1;
#pragma unroll
  for (int off = 32; off; off >>= 1) sm += __shfl_xor(sm, off);
  if ((t & 63) == 0) rs[t >> 6] = sm;
  __syncthreads();
  float inv = 1.f / (rs[0] + rs[1] + rs[2] + rs[3]);
  float a0 = e0 * inv, a1 = e1 * inv;
  attw[(size_t)bh * S + t] = a0;
  attw[(size_t)bh * S + t + 256] = a1;
  att_out[((size_t)b * S + t) * H + h] = a0;
  att_out[((size_t)b * S + t + 256) * H + h] = a1;
}

// ---------------- BK=64 single-buffer GEMM core (r11-verified >= BK=32).
// Chunk = 8 rows x 64 k (1KB); swizzle g^=(row&7); 2 barriers per 64-K phase.
template <int KD>
__device__ __forceinline__ void gemm_tile_gl64(const unsigned short* __restrict__ A,
                                               const unsigned short* __restrict__ Bt,
                                               int lda, int ldb, int m0, int n0,
                                               unsigned short* As, unsigned short* Bs, v4f acc[4][4]) {
  const int t = threadIdx.x;
  const int l = t & 63, w = t >> 6;
  const int wr = w >> 1, wc = w & 1;
  const int ch = l >> 4, r15 = l & 15;
  const int lr = l >> 3, lg = l & 7;  // staging: row-in-chunk, lane granule
  for (int kc = 0; kc < KD; kc += 64) {
#pragma unroll
    for (int cc = 0; cc < 4; ++cc) {
      int c = w * 4 + cc;  // chunk of 8 rows x 64k = 1 KB; A and B each 16 chunks
      int row = c * 8 + lr;
      int sg = lg ^ (row & 7);  // inverse-swizzled source granule
      gl_lds16(A + (size_t)(m0 + row) * lda + kc + sg * 8, As + c * 512);
      gl_lds16(Bt + (size_t)(n0 + row) * ldb + kc + sg * 8, Bs + c * 512);
    }
    __syncthreads();  // drains vmcnt(0): tile visible
#pragma unroll
    for (int kk = 0; kk < 2; ++kk) {
      v8s af[4], bfr[4];
#pragma unroll
      for (int i = 0; i < 4; ++i) {
        int ra = wr * 64 + i * 16 + r15;
        af[i] = *(const v8s*)(As + ra * 64 + (((kk * 4 + ch) ^ (ra & 7)) * 8));
        int rb = wc * 64 + i * 16 + r15;
        bfr[i] = *(const v8s*)(Bs + rb * 64 + (((kk * 4 + ch) ^ (rb & 7)) * 8));
      }
      __builtin_amdgcn_s_setprio(1);
#pragma unroll
      for (int i = 0; i < 4; ++i)
#pragma unroll
        for (int j = 0; j < 4; ++j)
          acc[i][j] = __builtin_amdgcn_mfma_f32_16x16x32_bf16(af[i], bfr[j], acc[i][j], 0, 0, 0);
      __builtin_amdgcn_s_setprio(0);
    }
    __syncthreads();  // all reads done before next stage overwrites
  }
}

// V-projection GEMM (BK=64): vb = bf16((xb @ wv)*attw); slotted-padded sqnorm atomics
__global__ __launch_bounds__(256) void k_gemm_v(const unsigned short* __restrict__ xb,
                                                const unsigned short* __restrict__ wvt,
                                                const float* __restrict__ attw,
                                                unsigned short* __restrict__ vb,
                                                float* __restrict__ sqnorm_p) {
  __shared__ alignas(16) unsigned short As[8192], Bs[8192];
  int m0 = blockIdx.x * 128, n0 = blockIdx.y * 128;
  v4f acc[4][4] = {};
  gemm_tile_gl64<512>(xb, wvt, 512, 512, m0, n0, As, Bs, acc);
  int t = threadIdx.x, l = t & 63, w = t >> 6, wr = w >> 1, wc = w & 1;
  int h = blockIdx.y * 2 + wc;
  float ssq = 0.f;
#pragma unroll
  for (int i = 0; i < 4; ++i) {
#pragma unroll
    for (int q = 0; q < 4; ++q) {
      int row = m0 + wr * 64 + i * 16 + (l >> 4) * 4 + q;
      int b = row >> 9, s = row & 511;
      float aw = attw[(size_t)(b * 8 + h) * 512 + s];
#pragma unroll
      for (int j = 0; j < 4; ++j) {
        int gc = n0 + wc * 64 + j * 16 + (l & 15);
        float o = acc[i][j][q] * aw;
        ssq += o * o;
        vb[(size_t)row * 512 + gc] = f2bf(o);
      }
    }
  }
#pragma unroll
  for (int off = 32; off; off >>= 1) ssq += __shfl_xor(ssq, off);
  // 64 slots on 64 distinct cache lines: slot (h, blockIdx.x&7)
  if (l == 0) atomicAdd(&sqnorm_p[(h * 8 + (blockIdx.x & 7)) * 16], ssq);
}

// LN0 (wave per row, IN-PLACE over xb): xh := bf16(LN(perm(vb)*hs + xh))
__global__ __launch_bounds__(256) void k_ln0(const unsigned short* __restrict__ vb,
                                             unsigned short* xh,
                                             const float* __restrict__ sqnorm_p, const float* __restrict__ g,
                                             const float* __restrict__ bb) {
  __shared__ unsigned short perm[4][512];
  __shared__ float hss[8];
  int t = threadIdx.x, w = t >> 6, l = t & 63;
  int r = blockIdx.x * 4 + w;
  *(v8s*)&perm[w][l * 8] = *(const v8s*)(vb + (size_t)r * 512 + l * 8);
  if (t < 8) {
    float s = 0.f;
#pragma unroll
    for (int c = 0; c < 8; ++c) s += sqnorm_p[(t * 8 + c) * 16];
    hss[t] = rsqrtf(fmaxf(s, 1e-12f));
  }
  __syncthreads();
  v8s xv = *(const v8s*)(xh + (size_t)r * 512 + l * 8);
  float v[8];
#pragma unroll
  for (int j = 0; j < 8; ++j) {
    v[j] = bf2f(perm[w][j * 64 + l]) * hss[j] + bf2f((unsigned short)xv[j]);
  }
  float sum = 0.f, sq = 0.f;
#pragma unroll
  for (int j = 0; j < 8; ++j) { sum += v[j]; sq += v[j] * v[j]; }
#pragma unroll
  for (int off = 32; off; off >>= 1) {
    sum += __shfl_xor(sum, off);
    sq += __shfl_xor(sq, off);
  }
  float mean = sum * (1.f / E);
  float var = fmaxf(sq * (1.f / E) - mean * mean, 0.f);
  float rstd = rsqrtf(var + 1e-3f);
  float4 g0 = *(const float4*)(g + l * 8), g1 = *(const float4*)(g + l * 8 + 4);
  float4 b0 = *(const float4*)(bb + l * 8), b1 = *(const float4*)(bb + l * 8 + 4);
  float gg[8] = {g0.x, g0.y, g0.z, g0.w, g1.x, g1.y, g1.z, g1.w};
  float bbv[8] = {b0.x, b0.y, b0.z, b0.w, b1.x, b1.y, b1.z, b1.w};
  v8s hv;
#pragma unroll
  for (int j = 0; j < 8; ++j) hv[j] = (short)f2bf((v[j] - mean) * rstd * gg[j] + bbv[j]);
  *(v8s*)(xh + (size_t)r * 512 + l * 8) = hv;
}

// FFN1 (BK=64): p1 = bf16(leaky_relu(hb @ w1 + b1)); rsump partial sumsq
__global__ __launch_bounds__(256) void k_ffn1(const unsigned short* __restrict__ hb,
                                              const unsigned short* __restrict__ w1t,
                                              const float* __restrict__ b1, unsigned short* __restrict__ p1,
                                              float* __restrict__ rsump) {
  __shared__ alignas(16) unsigned short As[8192], Bs[8192];
  int m0 = blockIdx.x * 128, n0 = blockIdx.y * 128;
  v4f acc[4][4] = {};
  gemm_tile_gl64<512>(hb, w1t, 512, 512, m0, n0, As, Bs, acc);
  int t = threadIdx.x, l = t & 63, w = t >> 6, wr = w >> 1, wc = w & 1;
  int colb = n0 + wc * 64 + (l & 15);
  float bias[4];
#pragma unroll
  for (int j = 0; j < 4; ++j) bias[j] = b1[colb + j * 16];
#pragma unroll
  for (int i = 0; i < 4; ++i) {
#pragma unroll
    for (int q = 0; q < 4; ++q) {
      int row = m0 + wr * 64 + i * 16 + (l >> 4) * 4 + q;
      float ps = 0.f;
#pragma unroll
      for (int j = 0; j < 4; ++j) {
        float v = acc[i][j][q] + bias[j];
        v = v > 0.f ? v : 0.2f * v;
        ps += v * v;
        p1[(size_t)row * FF + colb + j * 16] = f2bf(v);
      }
#pragma unroll
      for (int m = 1; m < 16; m <<= 1) ps += __shfl_xor(ps, m);
      if ((l & 15) == 0) rsump[(size_t)row * 24 + blockIdx.y * 2 + wc] = ps;
    }
  }
}

// FFN2 (BK=64): p2b = bf16((p1 @ w2)*rinv + b2 + hb); rinv computed in-block
__global__ __launch_bounds__(256) void k_ffn2(const unsigned short* __restrict__ p1,
                                              const unsigned short* __restrict__ w2t,
                                              const float* __restrict__ rsump, const float* __restrict__ b2,
                                              const unsigned short* __restrict__ hb,
                                              unsigned short* __restrict__ p2b) {
  __shared__ alignas(16) unsigned short As[8192], Bs[8192];
  __shared__ float rinv_l[128];
  int m0 = blockIdx.x * 128, n0 = blockIdx.y * 128;
  int t = threadIdx.x;
  if (t < 128) {
    float s = 0.f;
#pragma unroll
    for (int k = 0; k < 24; ++k) s += rsump[(size_t)(m0 + t) * 24 + k];
    rinv_l[t] = rsqrtf(fmaxf(s, 1e-12f));
  }
  v4f acc[4][4] = {};
  gemm_tile_gl64<1536>(p1, w2t, 1536, 1536, m0, n0, As, Bs, acc);
  int l = t & 63, w = t >> 6, wr = w >> 1, wc = w & 1;
  int colb = n0 + wc * 64 + (l & 15);
  float bias[4];
#pragma unroll
  for (int j = 0; j < 4; ++j) bias[j] = b2[colb + j * 16];
#pragma unroll
  for (int i = 0; i < 4; ++i) {
#pragma unroll
    for (int q = 0; q < 4; ++q) {
      int row = m0 + wr * 64 + i * 16 + (l >> 4) * 4 + q;
      float rv = rinv_l[row - m0];
#pragma unroll
      for (int j = 0; j < 4; ++j) {
        size_t idx = (size_t)row * 512 + colb + j * 16;
        float o = acc[i][j][q] * rv + bias[j] + bf2f(hb[idx]);
        p2b[idx] = f2bf(o);
      }
    }
  }
}

// LN1 (wave per row): out = LN(p2b)
__global__ __launch_bounds__(256) void k_ln1(const unsigned short* __restrict__ p2b, const float* __restrict__ g,
                                             const float* __restrict__ bb, float* __restrict__ outp) {
  int t = threadIdx.x, w = t >> 6, l = t & 63;
  int r = blockIdx.x * 4 + w;
  v8s pv = *(const v8s*)(p2b + (size_t)r * 512 + l * 8);
  float v[8];
#pragma unroll
  for (int j = 0; j < 8; ++j) v[j] = bf2f((unsigned short)pv[j]);
  float sum = 0.f, sq = 0.f;
#pragma unroll
  for (int j = 0; j < 8; ++j) { sum += v[j]; sq += v[j] * v[j]; }
#pragma unroll
  for (int off = 32; off; off >>= 1) {
    sum += __shfl_xor(sum, off);
    sq += __shfl_xor(sq, off);
  }
  float mean = sum * (1.f / E);
  float var = fmaxf(sq * (1.f / E) - mean * mean, 0.f);
  float rstd = rsqrtf(var + 1e-3f);
  float4 g0 = *(const float4*)(g + l * 8), g1 = *(const float4*)(g + l * 8 + 4);
  float4 b0 = *(const float4*)(bb + l * 8), b1 = *(const float4*)(bb + l * 8 + 4);
  float gg[8] = {g0.x, g0.y, g0.z, g0.w, g1.x, g1.y, g1.z, g1.w};
  float bbv[8] = {b0.x, b0.y, b0.z, b0.w, b1.x, b1.y, b1.z, b1.w};
  float4 o0, o1;
  o0.x = (v[0] - mean) * rstd * gg[0] + bbv[0];
  o0.y = (v[1] - mean) * rstd * gg[1] + bbv[1];
  o0.z = (v[2] - mean) * rstd * gg[2] + bbv[2];
  o0.w = (v[3] - mean) * rstd * gg[3] + bbv[3];
  o1.x = (v[4] - mean) * rstd * gg[4] + bbv[4];
  o1.y = (v[5] - mean) * rstd * gg[5] + bbv[5];
  o1.z = (v[6] - mean) * rstd * gg[6] + bbv[6];
  o1.w = (v[7] - mean) * rstd * gg[7] + bbv[7];
  *(float4*)(outp + (size_t)r * 512 + l * 8) = o0;
  *(float4*)(outp + (size_t)r * 512 + l * 8 + 4) = o1;
}

}  // namespace

extern "C" void kernel_launch(void* const* d_in, const int* in_sizes, int n_in,
                              void* d_out, int out_size, void* d_ws, size_t ws_size,
                              hipStream_t stream) {
  const float* x = (const float*)d_in[0];
  const float* wq = (const float*)d_in[1];
  const float* wk = (const float*)d_in[2];
  const float* wv = (const float*)d_in[3];
  const float* ln0_g = (const float*)d_in[4];
  const float* ln0_b = (const float*)d_in[5];
  const float* w1 = (const float*)d_in[6];
  const float* b1 = (const float*)d_in[7];
  const float* w2 = (const float*)d_in[8];
  const float* b2 = (const float*)d_in[9];
  const float* ln1_g = (const float*)d_in[10];
  const float* ln1_b = (const float*)d_in[11];

  float* att_out = (float*)d_out;                  // [B,S,H]
  float* outp = (float*)d_out + (size_t)B * S * H; // [B,S,E]

  char* ws = (char*)d_ws;
  float* xsump = (float*)(ws + 0);                        // 1 MB  [B][16][E]
  float* wqkb = (float*)(ws + 1048576);                   // 512 KB
  float* scores = (float*)(ws + 1572864);                 // 512 KB
  float* attw = (float*)(ws + 2097152);                   // 512 KB
  float* sqnorm_p = (float*)(ws + 2621440);               // 4 KB (64 slots x 64B)
  float* rsump = (float*)(ws + 2625536);                  // 1.5 MB [BS][24]
  unsigned short* w1t = (unsigned short*)(ws + 4263936);  // 1.5 MB [FF][E]
  unsigned short* w2t = (unsigned short*)(ws + 5836800);  // 1.5 MB [E][FF]
  unsigned short* wvt = (unsigned short*)(ws + 7409664);  // 512 KB [H*P][E]
  unsigned short* xb = (unsigned short*)(ws + 7933952);   // 16 MB [BS][E] bf16 (hb aliases after ln0)
  unsigned short* vb = (unsigned short*)(ws + 24711168);  // 16 MB [BS][512] bf16 (p2b aliases)
  unsigned short* p1 = (unsigned short*)(ws + 41488384);  // 48 MB [BS][FF] bf16
  unsigned short* hb = xb;                                // ln0 writes in place
  unsigned short* p2b = vb;                               // vb dead after ln0

  k_prep<<<704, 256, 0, stream>>>(w1, w2, wv, x, w1t, w2t, wvt, xb, xsump);
  k_wqk<<<dim3(B, H), 256, 0, stream>>>(xsump, wq, wk, wqkb, sqnorm_p);
  k_scores<<<dim3(B, S / 64), 256, 0, stream>>>(xb, wqkb, scores);
  k_softmax<<<B * H, 256, 0, stream>>>(scores, attw, att_out);
  k_gemm_v<<<dim3(BS / 128, 4), 256, 0, stream>>>(xb, wvt, attw, vb, sqnorm_p);
  k_ln0<<<BS / 4, 256, 0, stream>>>(vb, xb, sqnorm_p, ln0_g, ln0_b);
  k_ffn1<<<dim3(BS / 128, FF / 128), 256, 0, stream>>>(hb, w1t, b1, p1, rsump);
  k_ffn2<<<dim3(BS / 128, E / 128), 256, 0, stream>>>(p1, w2t, rsump, b2, hb, p2b);
  k_ln1<<<BS / 4, 256, 0, stream>>>(p2b, ln1_g, ln1_b, outp);
}